// Round 8
// baseline (703.341 us; speedup 1.0000x reference)
//
#include <hip/hip_runtime.h>
#include <hip/hip_bf16.h>
#include <math.h>

// ---------------------------------------------------------------------------
// DeepSeek MLA forward. Round 17 (= R16 resubmit; previous run died in the
// broker container before any dispatch — no data).
//  - R15 banked: BK=64 deep-K GEMMs (-22 us), attn on R9 fabric
//    (265 us, FETCH 122 MB — reproduced exactly).
//  - ONE change vs R15: attn block-ID remap for head->XCD affinity (T1).
//    xcd = bid & 7 (round-robin model); each XCD hosts heads {xcd, xcd+8}
//    only -> 3.2 MB KV + hot Q fits its 4 MB L2. Drains then wait on L2-hit
//    (~200cy) instead of HBM (~900cy). Heavy/light CU pairing preserved
//    (same-head complementary-qt blocks co-scheduled, 17 tiles/CU).
//    In-loop code bitwise identical to R9.
//  - Everything else byte-identical to R15.
// ---------------------------------------------------------------------------

#define T_DIM 2048
#define HEADS 16
#define D_MODEL 2048
#define NOPE_D 128
#define ROPE_D 64
#define QKD_D 192
#define VD_D 128
#define QLORA 768
#define KVLORA 512
#define KVFULL_D 576
#define SOFTSCALE -96.0f
#define EPS_RMS 1e-6f

typedef __hip_bfloat16 bf;
typedef __attribute__((ext_vector_type(8))) short bf16x8;
typedef __attribute__((ext_vector_type(4))) float f32x4;

#define GLOAD_LDS16(gptr, lptr)                                               \
    __builtin_amdgcn_global_load_lds(                                         \
        (const __attribute__((address_space(1))) unsigned int*)(gptr),        \
        (__attribute__((address_space(3))) unsigned int*)(lptr), 16, 0, 0)

__device__ __forceinline__ void split2(float v, bf* hi, bf* lo) {
    bf h = __float2bfloat16(v);
    *hi = h;
    *lo = __float2bfloat16(v - __bfloat162float(h));
}

// ---------------------------------------------------------------------------
__global__ __launch_bounds__(256) void cvt_split(
    const float* __restrict__ in, bf* __restrict__ hi, bf* __restrict__ lo, int n)
{
    const int i = (blockIdx.x * 256 + threadIdx.x) * 4;
    if (i >= n) return;
    float4 v = *(const float4*)&in[i];
    float vv[4] = {v.x, v.y, v.z, v.w};
#pragma unroll
    for (int u = 0; u < 4; u++) split2(vv[u], &hi[i + u], &lo[i + u]);
}

__global__ __launch_bounds__(256) void cvt_hi(
    const float* __restrict__ in, bf* __restrict__ hi, int n)
{
    const int i = (blockIdx.x * 256 + threadIdx.x) * 4;
    if (i >= n) return;
    float4 v = *(const float4*)&in[i];
    hi[i + 0] = __float2bfloat16(v.x);
    hi[i + 1] = __float2bfloat16(v.y);
    hi[i + 2] = __float2bfloat16(v.z);
    hi[i + 3] = __float2bfloat16(v.w);
}

// ---------------------------------------------------------------------------
__global__ __launch_bounds__(256) void rmsnorm_cvt(
    const float* __restrict__ in, int ld, int D, const float* __restrict__ w,
    bf* __restrict__ hi, bf* __restrict__ lo)
{
    const int row = blockIdx.x;
    const float* r = in + (size_t)row * ld;
    float ss = 0.0f;
    for (int i = threadIdx.x; i < D; i += 256) { float v = r[i]; ss += v * v; }
#pragma unroll
    for (int o = 32; o > 0; o >>= 1) ss += __shfl_down(ss, o, 64);
    __shared__ float red[4];
    if ((threadIdx.x & 63) == 0) red[threadIdx.x >> 6] = ss;
    __syncthreads();
    ss = red[0] + red[1] + red[2] + red[3];
    const float scale = rsqrtf(ss / (float)D + EPS_RMS);
    for (int i = threadIdx.x; i < D; i += 256) {
        const float v = r[i] * scale * w[i];
        split2(v, &hi[(size_t)row * D + i], &lo[(size_t)row * D + i]);
    }
}

// ---------------------------------------------------------------------------
__global__ __launch_bounds__(256) void rope_k_cvt(
    const float* __restrict__ kvfull, const float* __restrict__ freqs,
    bf* __restrict__ kpeh, bf* __restrict__ kpel)
{
    const int idx = blockIdx.x * 256 + threadIdx.x;   // 65536
    const int i = idx & 31, t = idx >> 5;
    const float f = freqs[t * 32 + i];
    float sn, cs; sincosf(f, &sn, &cs);
    const float x1 = kvfull[(size_t)t * KVFULL_D + KVLORA + 2 * i];
    const float x2 = kvfull[(size_t)t * KVFULL_D + KVLORA + 2 * i + 1];
    split2(x1 * cs - x2 * sn, &kpeh[t * 64 + 2 * i], &kpel[t * 64 + 2 * i]);
    split2(x1 * sn + x2 * cs, &kpeh[t * 64 + 2 * i + 1], &kpel[t * 64 + 2 * i + 1]);
}

// ---------------------------------------------------------------------------
__global__ __launch_bounds__(256) void transpose_v(
    const bf* __restrict__ vh, bf* __restrict__ vT)
{
    __shared__ bf s[32][33];
    const int t0 = blockIdx.x * 32, d0 = blockIdx.y * 32, h = blockIdx.z;
    const int tid = threadIdx.x;
    const int i = tid >> 3, j0 = (tid & 7) * 4;
    const bf* src = vh + ((size_t)(t0 + i) * 16 + h) * 128 + d0 + j0;
#pragma unroll
    for (int u = 0; u < 4; u++) s[i][j0 + u] = src[u];
    __syncthreads();
    const int jj = tid >> 3, i0 = (tid & 7) * 4;
    bf* dst = vT + ((size_t)h * 128 + d0 + jj) * 2048 + t0 + i0;
#pragma unroll
    for (int u = 0; u < 4; u++) dst[u] = s[i0 + u][jj];
}

// ---------------------------------------------------------------------------
// Split-bf16 GEMM (score path), 128x128 tile, 3 MFMAs.
// MODE 1: RoPE on d>=128 + split -> Oh/Ol (q). MODE 2: kn/v split write.
// ---------------------------------------------------------------------------
template <int MODE>
__global__ __launch_bounds__(256) void gemm_split(
    const bf* __restrict__ Ah, const bf* __restrict__ Al,
    const bf* __restrict__ Bh, const bf* __restrict__ Bl,
    const float* __restrict__ freqs,
    float* __restrict__ Cf, bf* __restrict__ Oh, bf* __restrict__ Ol,
    bf* __restrict__ O2, int M, int N, int K)
{
    __shared__ bf sAh[128 * 32], sAl[128 * 32];
    __shared__ bf sBh[128 * 32], sBl[128 * 32];

    const int tid = threadIdx.x;
    const int lane = tid & 63, wave = tid >> 6;
    const int row0 = blockIdx.y * 128, col0 = blockIdx.x * 128;
    const int wm = (wave & 1) * 64, wn = (wave >> 1) * 64;
    const int fr = lane & 15, quad = lane >> 4;

    f32x4 acc[4][4];
#pragma unroll
    for (int i = 0; i < 4; i++)
#pragma unroll
        for (int j = 0; j < 4; j++) acc[i][j] = (f32x4){0.f, 0.f, 0.f, 0.f};

    const int trow = tid >> 2;
    const int tcol = (tid & 3) * 8;
    const size_t ldsoff = (size_t)wave * 1024;

    for (int kt = 0; kt < K; kt += 32) {
        __syncthreads();
        GLOAD_LDS16(Ah + (size_t)(row0 + trow) * K + kt + tcol,      (char*)sAh + ldsoff);
        GLOAD_LDS16(Ah + (size_t)(row0 + 64 + trow) * K + kt + tcol, (char*)sAh + 4096 + ldsoff);
        GLOAD_LDS16(Al + (size_t)(row0 + trow) * K + kt + tcol,      (char*)sAl + ldsoff);
        GLOAD_LDS16(Al + (size_t)(row0 + 64 + trow) * K + kt + tcol, (char*)sAl + 4096 + ldsoff);
        GLOAD_LDS16(Bh + (size_t)(col0 + trow) * K + kt + tcol,      (char*)sBh + ldsoff);
        GLOAD_LDS16(Bh + (size_t)(col0 + 64 + trow) * K + kt + tcol, (char*)sBh + 4096 + ldsoff);
        GLOAD_LDS16(Bl + (size_t)(col0 + trow) * K + kt + tcol,      (char*)sBl + ldsoff);
        GLOAD_LDS16(Bl + (size_t)(col0 + 64 + trow) * K + kt + tcol, (char*)sBl + 4096 + ldsoff);
        __syncthreads();

        bf16x8 a_h[4], a_l[4], b_h[4], b_l[4];
#pragma unroll
        for (int mt = 0; mt < 4; mt++) {
            const int r = (wm + mt * 16 + fr) * 32 + quad * 8;
            a_h[mt] = *(const bf16x8*)&sAh[r];
            a_l[mt] = *(const bf16x8*)&sAl[r];
        }
#pragma unroll
        for (int nt = 0; nt < 4; nt++) {
            const int r = (wn + nt * 16 + fr) * 32 + quad * 8;
            b_h[nt] = *(const bf16x8*)&sBh[r];
            b_l[nt] = *(const bf16x8*)&sBl[r];
        }
#pragma unroll
        for (int mt = 0; mt < 4; mt++)
#pragma unroll
            for (int nt = 0; nt < 4; nt++) {
                acc[mt][nt] = __builtin_amdgcn_mfma_f32_16x16x32_bf16(
                    a_l[mt], b_h[nt], acc[mt][nt], 0, 0, 0);
                acc[mt][nt] = __builtin_amdgcn_mfma_f32_16x16x32_bf16(
                    a_h[mt], b_l[nt], acc[mt][nt], 0, 0, 0);
                acc[mt][nt] = __builtin_amdgcn_mfma_f32_16x16x32_bf16(
                    a_h[mt], b_h[nt], acc[mt][nt], 0, 0, 0);
            }
    }

#pragma unroll
    for (int mt = 0; mt < 4; mt++)
#pragma unroll
        for (int nt = 0; nt < 4; nt++) {
            const int colb = col0 + wn + nt * 16;
            const int col = colb + fr;
            if (MODE == 1) {
                const int d0 = colb % 192;
                const bool rope = (d0 >= 128);
                const int ii = (d0 + fr - 128) >> 1;
#pragma unroll
                for (int r = 0; r < 4; r++) {
                    const int row = row0 + wm + mt * 16 + quad * 4 + r;
                    float v = acc[mt][nt][r];
                    if (rope) {
                        const float other = __shfl_xor(v, 1);
                        float sn, cs; sincosf(freqs[row * 32 + ii], &sn, &cs);
                        v = (fr & 1) ? (other * sn + v * cs) : (v * cs - other * sn);
                    }
                    bf h8, l8; split2(v, &h8, &l8);
                    Oh[(size_t)row * N + col] = h8;
                    Ol[(size_t)row * N + col] = l8;
                }
            } else {
                const int hh = col >> 8;
                const int d = col & 255;
#pragma unroll
                for (int r = 0; r < 4; r++) {
                    const int row = row0 + wm + mt * 16 + quad * 4 + r;
                    const float v = acc[mt][nt][r];
                    if (d < 128) {
                        bf h8, l8; split2(v, &h8, &l8);
                        Oh[(size_t)row * 2048 + hh * 128 + d] = h8;
                        Ol[(size_t)row * 2048 + hh * 128 + d] = l8;
                    } else {
                        O2[(size_t)row * 2048 + hh * 128 + (d - 128)] = __float2bfloat16(v);
                    }
                }
            }
        }
}

// ---------------------------------------------------------------------------
// Split-bf16 GEMM, 64x64 tile, BK=64 (R15): halves drain-barrier count on the
// two K=2048 shapes (qa N=768, kvfull N=576). LDS [2 ks][64][32] per array.
// ---------------------------------------------------------------------------
__global__ __launch_bounds__(256) void gemm_split64(
    const bf* __restrict__ Ah, const bf* __restrict__ Al,
    const bf* __restrict__ Bh, const bf* __restrict__ Bl,
    float* __restrict__ Cf, int M, int N, int K)
{
    __shared__ bf sAh[2 * 64 * 32], sAl[2 * 64 * 32];
    __shared__ bf sBh[2 * 64 * 32], sBl[2 * 64 * 32];

    const int tid = threadIdx.x;
    const int lane = tid & 63, wave = tid >> 6;
    const int row0 = blockIdx.y * 64, col0 = blockIdx.x * 64;
    const int wm = (wave & 1) * 32, wn = (wave >> 1) * 32;
    const int fr = lane & 15, quad = lane >> 4;

    f32x4 acc[2][2];
#pragma unroll
    for (int i = 0; i < 2; i++)
#pragma unroll
        for (int j = 0; j < 2; j++) acc[i][j] = (f32x4){0.f, 0.f, 0.f, 0.f};

    const int trow = tid >> 2;
    const int tcol = (tid & 3) * 8;
    const size_t ldsoff = (size_t)wave * 1024;

    for (int kt = 0; kt < K; kt += 64) {
        __syncthreads();
        GLOAD_LDS16(Ah + (size_t)(row0 + trow) * K + kt + tcol,      (char*)sAh + ldsoff);
        GLOAD_LDS16(Ah + (size_t)(row0 + trow) * K + kt + 32 + tcol, (char*)sAh + 4096 + ldsoff);
        GLOAD_LDS16(Al + (size_t)(row0 + trow) * K + kt + tcol,      (char*)sAl + ldsoff);
        GLOAD_LDS16(Al + (size_t)(row0 + trow) * K + kt + 32 + tcol, (char*)sAl + 4096 + ldsoff);
        GLOAD_LDS16(Bh + (size_t)(col0 + trow) * K + kt + tcol,      (char*)sBh + ldsoff);
        GLOAD_LDS16(Bh + (size_t)(col0 + trow) * K + kt + 32 + tcol, (char*)sBh + 4096 + ldsoff);
        GLOAD_LDS16(Bl + (size_t)(col0 + trow) * K + kt + tcol,      (char*)sBl + ldsoff);
        GLOAD_LDS16(Bl + (size_t)(col0 + trow) * K + kt + 32 + tcol, (char*)sBl + 4096 + ldsoff);
        __syncthreads();

#pragma unroll
        for (int ks = 0; ks < 2; ks++) {
            bf16x8 a_h[2], a_l[2], b_h[2], b_l[2];
#pragma unroll
            for (int mt = 0; mt < 2; mt++) {
                const int r = ks * 2048 + (wm + mt * 16 + fr) * 32 + quad * 8;
                a_h[mt] = *(const bf16x8*)&sAh[r];
                a_l[mt] = *(const bf16x8*)&sAl[r];
            }
#pragma unroll
            for (int nt = 0; nt < 2; nt++) {
                const int r = ks * 2048 + (wn + nt * 16 + fr) * 32 + quad * 8;
                b_h[nt] = *(const bf16x8*)&sBh[r];
                b_l[nt] = *(const bf16x8*)&sBl[r];
            }
#pragma unroll
            for (int mt = 0; mt < 2; mt++)
#pragma unroll
                for (int nt = 0; nt < 2; nt++) {
                    acc[mt][nt] = __builtin_amdgcn_mfma_f32_16x16x32_bf16(
                        a_l[mt], b_h[nt], acc[mt][nt], 0, 0, 0);
                    acc[mt][nt] = __builtin_amdgcn_mfma_f32_16x16x32_bf16(
                        a_h[mt], b_l[nt], acc[mt][nt], 0, 0, 0);
                    acc[mt][nt] = __builtin_amdgcn_mfma_f32_16x16x32_bf16(
                        a_h[mt], b_h[nt], acc[mt][nt], 0, 0, 0);
                }
        }
    }

#pragma unroll
    for (int mt = 0; mt < 2; mt++)
#pragma unroll
        for (int nt = 0; nt < 2; nt++)
#pragma unroll
            for (int r = 0; r < 4; r++)
                Cf[(size_t)(row0 + wm + mt * 16 + quad * 4 + r) * N +
                   col0 + wn + nt * 16 + fr] = acc[mt][nt][r];
}

// ---------------------------------------------------------------------------
// Plain bf16 GEMM (post-softmax out-projection): C = A @ B^T, single MFMA.
// BK=64 (R15): halves drain-barrier count (K=2048). LDS [2 ks][128][32]/array.
// ---------------------------------------------------------------------------
__global__ __launch_bounds__(256) void gemm_bf16(
    const bf* __restrict__ Ah, const bf* __restrict__ Bh,
    float* __restrict__ Cf, int M, int N, int K)
{
    __shared__ bf sAh[2 * 128 * 32];
    __shared__ bf sBh[2 * 128 * 32];

    const int tid = threadIdx.x;
    const int lane = tid & 63, wave = tid >> 6;
    const int row0 = blockIdx.y * 128, col0 = blockIdx.x * 128;
    const int wm = (wave & 1) * 64, wn = (wave >> 1) * 64;
    const int fr = lane & 15, quad = lane >> 4;

    f32x4 acc[4][4];
#pragma unroll
    for (int i = 0; i < 4; i++)
#pragma unroll
        for (int j = 0; j < 4; j++) acc[i][j] = (f32x4){0.f, 0.f, 0.f, 0.f};

    const int trow = tid >> 2;
    const int tcol = (tid & 3) * 8;
    const size_t ldsoff = (size_t)wave * 1024;

    for (int kt = 0; kt < K; kt += 64) {
        __syncthreads();
        GLOAD_LDS16(Ah + (size_t)(row0 + trow) * K + kt + tcol,           (char*)sAh + ldsoff);
        GLOAD_LDS16(Ah + (size_t)(row0 + 64 + trow) * K + kt + tcol,      (char*)sAh + 4096 + ldsoff);
        GLOAD_LDS16(Ah + (size_t)(row0 + trow) * K + kt + 32 + tcol,      (char*)sAh + 8192 + ldsoff);
        GLOAD_LDS16(Ah + (size_t)(row0 + 64 + trow) * K + kt + 32 + tcol, (char*)sAh + 12288 + ldsoff);
        GLOAD_LDS16(Bh + (size_t)(col0 + trow) * K + kt + tcol,           (char*)sBh + ldsoff);
        GLOAD_LDS16(Bh + (size_t)(col0 + 64 + trow) * K + kt + tcol,      (char*)sBh + 4096 + ldsoff);
        GLOAD_LDS16(Bh + (size_t)(col0 + trow) * K + kt + 32 + tcol,      (char*)sBh + 8192 + ldsoff);
        GLOAD_LDS16(Bh + (size_t)(col0 + 64 + trow) * K + kt + 32 + tcol, (char*)sBh + 12288 + ldsoff);
        __syncthreads();

#pragma unroll
        for (int ks = 0; ks < 2; ks++) {
            bf16x8 a_h[4], b_h[4];
#pragma unroll
            for (int mt = 0; mt < 4; mt++)
                a_h[mt] = *(const bf16x8*)&sAh[ks * 4096 + (wm + mt * 16 + fr) * 32 + quad * 8];
#pragma unroll
            for (int nt = 0; nt < 4; nt++)
                b_h[nt] = *(const bf16x8*)&sBh[ks * 4096 + (wn + nt * 16 + fr) * 32 + quad * 8];
#pragma unroll
            for (int mt = 0; mt < 4; mt++)
#pragma unroll
                for (int nt = 0; nt < 4; nt++)
                    acc[mt][nt] = __builtin_amdgcn_mfma_f32_16x16x32_bf16(
                        a_h[mt], b_h[nt], acc[mt][nt], 0, 0, 0);
        }
    }

#pragma unroll
    for (int mt = 0; mt < 4; mt++)
#pragma unroll
        for (int nt = 0; nt < 4; nt++)
#pragma unroll
            for (int r = 0; r < 4; r++)
                Cf[(size_t)(row0 + wm + mt * 16 + quad * 4 + r) * N +
                   col0 + wn + nt * 16 + fr] = acc[mt][nt][r];
}

// ---------------------------------------------------------------------------
// Monolithic MFMA flash attention (R9 fabric + head->XCD block remap).
// 512 blocks; xcd = bid & 7 hosts heads {xcd, xcd+8} only -> per-XCD L2
// holds the head-pair's KV (3.2 MB) + hot Q. Heavy/light pairing preserved:
// same-head complementary-qt blocks co-scheduled (17 k-tiles per CU).
// In-loop code identical to R9: ping-pong staged S (6 chunks x 1 barrier),
// fp32 online softmax, PV with padded Ps + preloaded V. LDS 60.4 KB.
// ---------------------------------------------------------------------------
__global__ __launch_bounds__(256, 2) void attn_mfma(
    const bf* __restrict__ qh, const bf* __restrict__ ql,
    const bf* __restrict__ knh, const bf* __restrict__ knl,
    const bf* __restrict__ kpeh, const bf* __restrict__ kpel,
    const bf* __restrict__ vT, bf* __restrict__ yh)
{
    const int bid = blockIdx.x;
    // head->XCD affinity remap (round-robin model: XCD = bid & 7)
    const int xcd  = bid & 7;
    const int slot = bid >> 3;          // 0..63 within this XCD
    const int half = slot >> 5;         // 0 = heavy, 1 = light
    const int j    = slot & 31;
    const int h    = xcd + 8 * (j >> 4);
    const int i_   = j & 15;
    const int qt   = half ? i_ : (31 - i_);

    const int tid = threadIdx.x;
    const int lane = tid & 63, wave = tid >> 6;
    const int fr = lane & 15, quad = lane >> 4;
    const int wn = wave * 32;

    // buf0 @0, buf1 @24576 (each: Qh 0 / Ql 4096 / Kh 8192 / Kl 16384)
    // sVt aliases buf0[0:16384] during PV. Ps @49152 ([64][72] bf16).
    __shared__ __align__(16) char smem[60416];
    bf* Ps  = (bf*)(smem + 49152);
    float* redM = (float*)(smem + 58368); // [64][4]
    float* redS = (float*)(smem + 59392); // [64][4]

    float m_i[16], l_i[16], al[16];
    f32x4 O[4][2];
#pragma unroll
    for (int i = 0; i < 16; i++) { m_i[i] = -INFINITY; l_i[i] = 0.0f; }
#pragma unroll
    for (int mt = 0; mt < 4; mt++)
#pragma unroll
        for (int nt = 0; nt < 2; nt++) O[mt][nt] = (f32x4){0.f, 0.f, 0.f, 0.f};

    const int q0 = qt * 64;
    const int nkt = ((qt + 1) * 64 + 127) >> 7;
    const int trow = tid >> 2, tcol = (tid & 3) * 8;
    const size_t loff = (size_t)wave * 1024;

    for (int kt = 0; kt < nkt; kt++) {
        const int k0 = kt * 128;
        f32x4 S[4][2];
#pragma unroll
        for (int mt = 0; mt < 4; mt++)
#pragma unroll
            for (int nt = 0; nt < 2; nt++) S[mt][nt] = (f32x4){0.f, 0.f, 0.f, 0.f};

        // leading barrier: prior k-tile's PV readers of buf0 (sVt alias) done
        __syncthreads();

        // ---- S = Q.K^T over 192 dims: 6 chunks, ping-pong, 1 barrier each --
        for (int ch = 0; ch < 6; ch++) {
            const int d0 = ch * 32;
            char* buf = smem + ((ch & 1) ? 24576 : 0);
            GLOAD_LDS16(qh + ((size_t)(q0 + trow) * 16 + h) * 192 + d0 + tcol, buf + loff);
            GLOAD_LDS16(ql + ((size_t)(q0 + trow) * 16 + h) * 192 + d0 + tcol, buf + 4096 + loff);
            if (d0 < 128) {
                GLOAD_LDS16(knh + ((size_t)(k0 + trow) * 16 + h) * 128 + d0 + tcol,      buf + 8192 + loff);
                GLOAD_LDS16(knh + ((size_t)(k0 + 64 + trow) * 16 + h) * 128 + d0 + tcol, buf + 12288 + loff);
                GLOAD_LDS16(knl + ((size_t)(k0 + trow) * 16 + h) * 128 + d0 + tcol,      buf + 16384 + loff);
                GLOAD_LDS16(knl + ((size_t)(k0 + 64 + trow) * 16 + h) * 128 + d0 + tcol, buf + 20480 + loff);
            } else {
                GLOAD_LDS16(kpeh + (size_t)(k0 + trow) * 64 + (d0 - 128) + tcol,      buf + 8192 + loff);
                GLOAD_LDS16(kpeh + (size_t)(k0 + 64 + trow) * 64 + (d0 - 128) + tcol, buf + 12288 + loff);
                GLOAD_LDS16(kpel + (size_t)(k0 + trow) * 64 + (d0 - 128) + tcol,      buf + 16384 + loff);
                GLOAD_LDS16(kpel + (size_t)(k0 + 64 + trow) * 64 + (d0 - 128) + tcol, buf + 20480 + loff);
            }
            __syncthreads();

            const bf* sQh = (const bf*)buf;
            const bf* sQl = (const bf*)(buf + 4096);
            const bf* sKh = (const bf*)(buf + 8192);
            const bf* sKl = (const bf*)(buf + 16384);
            bf16x8 a_h[4], a_l[4], b_h[2], b_l[2];
#pragma unroll
            for (int mt = 0; mt < 4; mt++) {
                const int r = (mt * 16 + fr) * 32 + quad * 8;
                a_h[mt] = *(const bf16x8*)&sQh[r];
                a_l[mt] = *(const bf16x8*)&sQl[r];
            }
#pragma unroll
            for (int nt = 0; nt < 2; nt++) {
                const int r = (wn + nt * 16 + fr) * 32 + quad * 8;
                b_h[nt] = *(const bf16x8*)&sKh[r];
                b_l[nt] = *(const bf16x8*)&sKl[r];
            }
#pragma unroll
            for (int mt = 0; mt < 4; mt++)
#pragma unroll
                for (int nt = 0; nt < 2; nt++) {
                    S[mt][nt] = __builtin_amdgcn_mfma_f32_16x16x32_bf16(
                        a_l[mt], b_h[nt], S[mt][nt], 0, 0, 0);
                    S[mt][nt] = __builtin_amdgcn_mfma_f32_16x16x32_bf16(
                        a_h[mt], b_l[nt], S[mt][nt], 0, 0, 0);
                    S[mt][nt] = __builtin_amdgcn_mfma_f32_16x16x32_bf16(
                        a_h[mt], b_h[nt], S[mt][nt], 0, 0, 0);
                }
        }

        // ---- online softmax (fp32, block-wide row reductions) ----
#pragma unroll
        for (int mt = 0; mt < 4; mt++)
#pragma unroll
            for (int rr = 0; rr < 4; rr++) {
                const int ri = mt * 16 + quad * 4 + rr;
                const int rowg = q0 + ri;
                float v0 = S[mt][0][rr] * SOFTSCALE;
                float v1 = S[mt][1][rr] * SOFTSCALE;
                if (k0 + wn + fr > rowg)      v0 = -INFINITY;
                if (k0 + wn + 16 + fr > rowg) v1 = -INFINITY;
                S[mt][0][rr] = v0; S[mt][1][rr] = v1;
                float pm = fmaxf(v0, v1);
#pragma unroll
                for (int o = 1; o < 16; o <<= 1) pm = fmaxf(pm, __shfl_xor(pm, o, 64));
                if (fr == 0) redM[ri * 4 + wave] = pm;
            }
        __syncthreads();
#pragma unroll
        for (int mt = 0; mt < 4; mt++)
#pragma unroll
            for (int rr = 0; rr < 4; rr++) {
                const int idx = mt * 4 + rr;
                const int ri = mt * 16 + quad * 4 + rr;
                const float4 g = *(const float4*)&redM[ri * 4];
                const float gm = fmaxf(fmaxf(g.x, g.y), fmaxf(g.z, g.w));
                const float mn = fmaxf(m_i[idx], gm);
                al[idx] = __expf(m_i[idx] - mn);
                m_i[idx] = mn;
                const float p0 = __expf(S[mt][0][rr] - mn);
                const float p1 = __expf(S[mt][1][rr] - mn);
                S[mt][0][rr] = p0; S[mt][1][rr] = p1;   // keep p for PV store
                float ps = p0 + p1;
#pragma unroll
                for (int o = 1; o < 16; o <<= 1) ps += __shfl_xor(ps, o, 64);
                if (fr == 0) redS[ri * 4 + wave] = ps;
            }
#pragma unroll
        for (int mt = 0; mt < 4; mt++)
#pragma unroll
            for (int nt = 0; nt < 2; nt++)
#pragma unroll
                for (int rr = 0; rr < 4; rr++) O[mt][nt][rr] *= al[mt * 4 + rr];
        __syncthreads();
#pragma unroll
        for (int mt = 0; mt < 4; mt++)
#pragma unroll
            for (int rr = 0; rr < 4; rr++) {
                const int idx = mt * 4 + rr;
                const int ri = mt * 16 + quad * 4 + rr;
                const float4 s4 = *(const float4*)&redS[ri * 4];
                l_i[idx] = l_i[idx] * al[idx] + (s4.x + s4.y + s4.z + s4.w);
            }

        // ---- PV: two 64-key halves; both 32-key V chunks preloaded ----
        bf* sVt = (bf*)smem;   // aliases buf0 (dead during PV)
#pragma unroll
        for (int half2 = 0; half2 < 2; half2++) {
            if (half2) __syncthreads();   // prior Ps/sVt readers done
            if ((wave >> 1) == half2) {
                const int kc = wn - half2 * 64;   // 0 or 32
#pragma unroll
                for (int mt = 0; mt < 4; mt++)
#pragma unroll
                    for (int rr = 0; rr < 4; rr++) {
                        const int ri = mt * 16 + quad * 4 + rr;
                        Ps[ri * 72 + kc + fr]      = __float2bfloat16(S[mt][0][rr]);
                        Ps[ri * 72 + kc + 16 + fr] = __float2bfloat16(S[mt][1][rr]);
                    }
            }
            const int kb = k0 + half2 * 64;
            GLOAD_LDS16(vT + ((size_t)(h * 128 + trow)) * 2048 + kb + tcol,           (char*)sVt + loff);
            GLOAD_LDS16(vT + ((size_t)(h * 128 + 64 + trow)) * 2048 + kb + tcol,      (char*)sVt + 4096 + loff);
            GLOAD_LDS16(vT + ((size_t)(h * 128 + trow)) * 2048 + kb + 32 + tcol,      (char*)sVt + 8192 + loff);
            GLOAD_LDS16(vT + ((size_t)(h * 128 + 64 + trow)) * 2048 + kb + 32 + tcol, (char*)sVt + 12288 + loff);
            __syncthreads();
#pragma unroll
            for (int vc = 0; vc < 2; vc++) {
                bf16x8 ap[4], bv[2];
#pragma unroll
                for (int mt = 0; mt < 4; mt++)
                    ap[mt] = *(const bf16x8*)&Ps[(mt * 16 + fr) * 72 + vc * 32 + quad * 8];
#pragma unroll
                for (int nt = 0; nt < 2; nt++)
                    bv[nt] = *(const bf16x8*)&sVt[vc * 4096 + (wn + nt * 16 + fr) * 32 + quad * 8];
#pragma unroll
                for (int mt = 0; mt < 4; mt++)
#pragma unroll
                    for (int nt = 0; nt < 2; nt++)
                        O[mt][nt] = __builtin_amdgcn_mfma_f32_16x16x32_bf16(
                            ap[mt], bv[nt], O[mt][nt], 0, 0, 0);
            }
        }
    }

    // ---- epilogue: y = O / l (bf16) ----
#pragma unroll
    for (int mt = 0; mt < 4; mt++)
#pragma unroll
        for (int rr = 0; rr < 4; rr++) {
            const float inv = 1.0f / l_i[mt * 4 + rr];
            const int row = q0 + mt * 16 + quad * 4 + rr;
#pragma unroll
            for (int nt = 0; nt < 2; nt++)
                yh[((size_t)row * 16 + h) * 128 + wn + nt * 16 + fr] =
                    __float2bfloat16(O[mt][nt][rr] * inv);
        }
}

// ---------------------------------------------------------------------------
// Workspace (peak < 85 MB):
//  A  @0        : xh(8.39) xl(8.39) -> yh@0, vT@8.39
//  AR @16.78    : (16.78) GEMM temporaries -> woh
//  persistent   : qh@33.55 ql@46.14 knh@58.72 knl@67.11 vh@75.50
//                 kpeh@83.89 kpel@84.15
// ---------------------------------------------------------------------------
extern "C" void kernel_launch(void* const* d_in, const int* in_sizes, int n_in,
                              void* d_out, int out_size, void* d_ws, size_t ws_size,
                              hipStream_t stream)
{
    const float* x        = (const float*)d_in[0];
    const float* freqs    = (const float*)d_in[1];
    const float* wq_a     = (const float*)d_in[3];
    const float* q_norm_w = (const float*)d_in[4];
    const float* wq_b     = (const float*)d_in[5];
    const float* wkv_a    = (const float*)d_in[6];
    const float* kv_norm_w= (const float*)d_in[7];
    const float* wkv_b    = (const float*)d_in[8];
    const float* wo       = (const float*)d_in[9];
    float* out            = (float*)d_out;

    char* ws = (char*)d_ws;
    bf* xh = (bf*)(ws);
    bf* xl = (bf*)(ws + 8388608);
    bf* yh = (bf*)(ws);                   // after x dead
    bf* vT = (bf*)(ws + 8388608);         // after x dead
    char* AR = ws + 16777216;
    bf*    wah    = (bf*)(AR);
    bf*    wal    = (bf*)(AR + 3145728);
    float* qa     = (float*)(AR + 6291456);
    bf*    qah    = (bf*)(AR);
    bf*    qal    = (bf*)(AR + 3145728);
    bf*    wbh    = (bf*)(AR + 6291456);
    bf*    wbl    = (bf*)(AR + 11010048);
    bf*    kah    = (bf*)(AR);
    bf*    kal    = (bf*)(AR + 2359296);
    float* kvfull = (float*)(AR + 4718592);
    bf*    ckvh   = (bf*)(AR + 9437184);
    bf*    ckvl   = (bf*)(AR + 11534336);
    bf*    wvh    = (bf*)(AR);
    bf*    wvl    = (bf*)(AR + 4194304);
    bf*    woh    = (bf*)(AR);
    bf* qh   = (bf*)(ws + 33554432);
    bf* ql   = (bf*)(ws + 46137344);
    bf* knh  = (bf*)(ws + 58720256);
    bf* knl  = (bf*)(ws + 67108864);
    bf* vh   = (bf*)(ws + 75497472);
    bf* kpeh = (bf*)(ws + 83886080);
    bf* kpel = (bf*)(ws + 84148224);

    dim3 blk(256);

    cvt_split<<<4096, blk, 0, stream>>>(x, xh, xl, D_MODEL * D_MODEL);
    cvt_split<<<1536, blk, 0, stream>>>(wq_a, wah, wal, QLORA * D_MODEL);
    gemm_split64<<<dim3(12, 32), blk, 0, stream>>>(
        xh, xl, wah, wal, qa, T_DIM, QLORA, D_MODEL);
    rmsnorm_cvt<<<T_DIM, blk, 0, stream>>>(qa, QLORA, QLORA, q_norm_w, qah, qal);
    cvt_split<<<2304, blk, 0, stream>>>(wq_b, wbh, wbl, 3072 * QLORA);
    gemm_split<1><<<dim3(24, 16), blk, 0, stream>>>(
        qah, qal, wbh, wbl, freqs, nullptr, qh, ql, nullptr,
        T_DIM, 3072, QLORA);
    cvt_split<<<1152, blk, 0, stream>>>(wkv_a, kah, kal, KVFULL_D * D_MODEL);
    gemm_split64<<<dim3(9, 32), blk, 0, stream>>>(
        xh, xl, kah, kal, kvfull, T_DIM, KVFULL_D, D_MODEL);
    rope_k_cvt<<<256, blk, 0, stream>>>(kvfull, freqs, kpeh, kpel);
    rmsnorm_cvt<<<T_DIM, blk, 0, stream>>>(kvfull, KVFULL_D, KVLORA, kv_norm_w, ckvh, ckvl);
    cvt_split<<<2048, blk, 0, stream>>>(wkv_b, wvh, wvl, 4096 * KVLORA);
    gemm_split<2><<<dim3(32, 16), blk, 0, stream>>>(
        ckvh, ckvl, wvh, wvl, nullptr, nullptr, knh, knl, vh,
        T_DIM, 4096, KVLORA);
    transpose_v<<<dim3(64, 4, 16), blk, 0, stream>>>(vh, vT);
    attn_mfma<<<dim3(512), blk, 0, stream>>>(
        qh, ql, knh, knl, kpeh, kpel, vT, yh);
    cvt_hi<<<4096, blk, 0, stream>>>(wo, woh, D_MODEL * D_MODEL);
    gemm_bf16<<<dim3(16, 16), blk, 0, stream>>>(
        yh, woh, out, T_DIM, D_MODEL, D_MODEL);
}

// Round 9
// 677.251 us; speedup vs baseline: 1.0385x; 1.0385x over previous
//
#include <hip/hip_runtime.h>
#include <hip/hip_bf16.h>
#include <math.h>

// ---------------------------------------------------------------------------
// DeepSeek MLA forward. Round 18:
//  - R16/R17 post-mortem: head->XCD remap FALSIFIED (FETCH 122->119.5,
//    unchanged) and cost +27 us (pairing disturbed). Reverted to R9 mapping.
//  - Model: attn is drain-count x queue-latency bound (8 expensive drains
//    per k-tile x 16 tiles x ~2100cy ~= the non-compute time; BW 7%, MFMA 7%).
//  - R18: fewer, fatter drains. QK staged in 3 chunks of 64 dims (was 6x32),
//    single 48 KB buffer (no ping-pong), pure drain discipline (zero
//    prefetch), same per-lane global addresses (grouped 2-at-a-time), same
//    block mapping, bitwise-identical MFMA accumulation order. Expensive
//    drains/tile 8 -> 5; 2 extra WAR barriers are vmcnt-0-already (cheap).
//    LDS layout: buf 48K (Qh0/Qh1/Ql0/Ql1 4K each, Kh 16K, Kl 16K),
//    Ps@49152, redM/redS — total 60416 B, identical to R9 -> 2 blocks/CU.
//  - GEMMs keep R15 BK=64. Everything else byte-identical to R15.
// ---------------------------------------------------------------------------

#define T_DIM 2048
#define HEADS 16
#define D_MODEL 2048
#define NOPE_D 128
#define ROPE_D 64
#define QKD_D 192
#define VD_D 128
#define QLORA 768
#define KVLORA 512
#define KVFULL_D 576
#define SOFTSCALE -96.0f
#define EPS_RMS 1e-6f

typedef __hip_bfloat16 bf;
typedef __attribute__((ext_vector_type(8))) short bf16x8;
typedef __attribute__((ext_vector_type(4))) float f32x4;

#define GLOAD_LDS16(gptr, lptr)                                               \
    __builtin_amdgcn_global_load_lds(                                         \
        (const __attribute__((address_space(1))) unsigned int*)(gptr),        \
        (__attribute__((address_space(3))) unsigned int*)(lptr), 16, 0, 0)

__device__ __forceinline__ void split2(float v, bf* hi, bf* lo) {
    bf h = __float2bfloat16(v);
    *hi = h;
    *lo = __float2bfloat16(v - __bfloat162float(h));
}

// ---------------------------------------------------------------------------
__global__ __launch_bounds__(256) void cvt_split(
    const float* __restrict__ in, bf* __restrict__ hi, bf* __restrict__ lo, int n)
{
    const int i = (blockIdx.x * 256 + threadIdx.x) * 4;
    if (i >= n) return;
    float4 v = *(const float4*)&in[i];
    float vv[4] = {v.x, v.y, v.z, v.w};
#pragma unroll
    for (int u = 0; u < 4; u++) split2(vv[u], &hi[i + u], &lo[i + u]);
}

__global__ __launch_bounds__(256) void cvt_hi(
    const float* __restrict__ in, bf* __restrict__ hi, int n)
{
    const int i = (blockIdx.x * 256 + threadIdx.x) * 4;
    if (i >= n) return;
    float4 v = *(const float4*)&in[i];
    hi[i + 0] = __float2bfloat16(v.x);
    hi[i + 1] = __float2bfloat16(v.y);
    hi[i + 2] = __float2bfloat16(v.z);
    hi[i + 3] = __float2bfloat16(v.w);
}

// ---------------------------------------------------------------------------
__global__ __launch_bounds__(256) void rmsnorm_cvt(
    const float* __restrict__ in, int ld, int D, const float* __restrict__ w,
    bf* __restrict__ hi, bf* __restrict__ lo)
{
    const int row = blockIdx.x;
    const float* r = in + (size_t)row * ld;
    float ss = 0.0f;
    for (int i = threadIdx.x; i < D; i += 256) { float v = r[i]; ss += v * v; }
#pragma unroll
    for (int o = 32; o > 0; o >>= 1) ss += __shfl_down(ss, o, 64);
    __shared__ float red[4];
    if ((threadIdx.x & 63) == 0) red[threadIdx.x >> 6] = ss;
    __syncthreads();
    ss = red[0] + red[1] + red[2] + red[3];
    const float scale = rsqrtf(ss / (float)D + EPS_RMS);
    for (int i = threadIdx.x; i < D; i += 256) {
        const float v = r[i] * scale * w[i];
        split2(v, &hi[(size_t)row * D + i], &lo[(size_t)row * D + i]);
    }
}

// ---------------------------------------------------------------------------
__global__ __launch_bounds__(256) void rope_k_cvt(
    const float* __restrict__ kvfull, const float* __restrict__ freqs,
    bf* __restrict__ kpeh, bf* __restrict__ kpel)
{
    const int idx = blockIdx.x * 256 + threadIdx.x;   // 65536
    const int i = idx & 31, t = idx >> 5;
    const float f = freqs[t * 32 + i];
    float sn, cs; sincosf(f, &sn, &cs);
    const float x1 = kvfull[(size_t)t * KVFULL_D + KVLORA + 2 * i];
    const float x2 = kvfull[(size_t)t * KVFULL_D + KVLORA + 2 * i + 1];
    split2(x1 * cs - x2 * sn, &kpeh[t * 64 + 2 * i], &kpel[t * 64 + 2 * i]);
    split2(x1 * sn + x2 * cs, &kpeh[t * 64 + 2 * i + 1], &kpel[t * 64 + 2 * i + 1]);
}

// ---------------------------------------------------------------------------
__global__ __launch_bounds__(256) void transpose_v(
    const bf* __restrict__ vh, bf* __restrict__ vT)
{
    __shared__ bf s[32][33];
    const int t0 = blockIdx.x * 32, d0 = blockIdx.y * 32, h = blockIdx.z;
    const int tid = threadIdx.x;
    const int i = tid >> 3, j0 = (tid & 7) * 4;
    const bf* src = vh + ((size_t)(t0 + i) * 16 + h) * 128 + d0 + j0;
#pragma unroll
    for (int u = 0; u < 4; u++) s[i][j0 + u] = src[u];
    __syncthreads();
    const int jj = tid >> 3, i0 = (tid & 7) * 4;
    bf* dst = vT + ((size_t)h * 128 + d0 + jj) * 2048 + t0 + i0;
#pragma unroll
    for (int u = 0; u < 4; u++) dst[u] = s[i0 + u][jj];
}

// ---------------------------------------------------------------------------
// Split-bf16 GEMM (score path), 128x128 tile, 3 MFMAs.
// MODE 1: RoPE on d>=128 + split -> Oh/Ol (q). MODE 2: kn/v split write.
// ---------------------------------------------------------------------------
template <int MODE>
__global__ __launch_bounds__(256) void gemm_split(
    const bf* __restrict__ Ah, const bf* __restrict__ Al,
    const bf* __restrict__ Bh, const bf* __restrict__ Bl,
    const float* __restrict__ freqs,
    float* __restrict__ Cf, bf* __restrict__ Oh, bf* __restrict__ Ol,
    bf* __restrict__ O2, int M, int N, int K)
{
    __shared__ bf sAh[128 * 32], sAl[128 * 32];
    __shared__ bf sBh[128 * 32], sBl[128 * 32];

    const int tid = threadIdx.x;
    const int lane = tid & 63, wave = tid >> 6;
    const int row0 = blockIdx.y * 128, col0 = blockIdx.x * 128;
    const int wm = (wave & 1) * 64, wn = (wave >> 1) * 64;
    const int fr = lane & 15, quad = lane >> 4;

    f32x4 acc[4][4];
#pragma unroll
    for (int i = 0; i < 4; i++)
#pragma unroll
        for (int j = 0; j < 4; j++) acc[i][j] = (f32x4){0.f, 0.f, 0.f, 0.f};

    const int trow = tid >> 2;
    const int tcol = (tid & 3) * 8;
    const size_t ldsoff = (size_t)wave * 1024;

    for (int kt = 0; kt < K; kt += 32) {
        __syncthreads();
        GLOAD_LDS16(Ah + (size_t)(row0 + trow) * K + kt + tcol,      (char*)sAh + ldsoff);
        GLOAD_LDS16(Ah + (size_t)(row0 + 64 + trow) * K + kt + tcol, (char*)sAh + 4096 + ldsoff);
        GLOAD_LDS16(Al + (size_t)(row0 + trow) * K + kt + tcol,      (char*)sAl + ldsoff);
        GLOAD_LDS16(Al + (size_t)(row0 + 64 + trow) * K + kt + tcol, (char*)sAl + 4096 + ldsoff);
        GLOAD_LDS16(Bh + (size_t)(col0 + trow) * K + kt + tcol,      (char*)sBh + ldsoff);
        GLOAD_LDS16(Bh + (size_t)(col0 + 64 + trow) * K + kt + tcol, (char*)sBh + 4096 + ldsoff);
        GLOAD_LDS16(Bl + (size_t)(col0 + trow) * K + kt + tcol,      (char*)sBl + ldsoff);
        GLOAD_LDS16(Bl + (size_t)(col0 + 64 + trow) * K + kt + tcol, (char*)sBl + 4096 + ldsoff);
        __syncthreads();

        bf16x8 a_h[4], a_l[4], b_h[4], b_l[4];
#pragma unroll
        for (int mt = 0; mt < 4; mt++) {
            const int r = (wm + mt * 16 + fr) * 32 + quad * 8;
            a_h[mt] = *(const bf16x8*)&sAh[r];
            a_l[mt] = *(const bf16x8*)&sAl[r];
        }
#pragma unroll
        for (int nt = 0; nt < 4; nt++) {
            const int r = (wn + nt * 16 + fr) * 32 + quad * 8;
            b_h[nt] = *(const bf16x8*)&sBh[r];
            b_l[nt] = *(const bf16x8*)&sBl[r];
        }
#pragma unroll
        for (int mt = 0; mt < 4; mt++)
#pragma unroll
            for (int nt = 0; nt < 4; nt++) {
                acc[mt][nt] = __builtin_amdgcn_mfma_f32_16x16x32_bf16(
                    a_l[mt], b_h[nt], acc[mt][nt], 0, 0, 0);
                acc[mt][nt] = __builtin_amdgcn_mfma_f32_16x16x32_bf16(
                    a_h[mt], b_l[nt], acc[mt][nt], 0, 0, 0);
                acc[mt][nt] = __builtin_amdgcn_mfma_f32_16x16x32_bf16(
                    a_h[mt], b_h[nt], acc[mt][nt], 0, 0, 0);
            }
    }

#pragma unroll
    for (int mt = 0; mt < 4; mt++)
#pragma unroll
        for (int nt = 0; nt < 4; nt++) {
            const int colb = col0 + wn + nt * 16;
            const int col = colb + fr;
            if (MODE == 1) {
                const int d0 = colb % 192;
                const bool rope = (d0 >= 128);
                const int ii = (d0 + fr - 128) >> 1;
#pragma unroll
                for (int r = 0; r < 4; r++) {
                    const int row = row0 + wm + mt * 16 + quad * 4 + r;
                    float v = acc[mt][nt][r];
                    if (rope) {
                        const float other = __shfl_xor(v, 1);
                        float sn, cs; sincosf(freqs[row * 32 + ii], &sn, &cs);
                        v = (fr & 1) ? (other * sn + v * cs) : (v * cs - other * sn);
                    }
                    bf h8, l8; split2(v, &h8, &l8);
                    Oh[(size_t)row * N + col] = h8;
                    Ol[(size_t)row * N + col] = l8;
                }
            } else {
                const int hh = col >> 8;
                const int d = col & 255;
#pragma unroll
                for (int r = 0; r < 4; r++) {
                    const int row = row0 + wm + mt * 16 + quad * 4 + r;
                    const float v = acc[mt][nt][r];
                    if (d < 128) {
                        bf h8, l8; split2(v, &h8, &l8);
                        Oh[(size_t)row * 2048 + hh * 128 + d] = h8;
                        Ol[(size_t)row * 2048 + hh * 128 + d] = l8;
                    } else {
                        O2[(size_t)row * 2048 + hh * 128 + (d - 128)] = __float2bfloat16(v);
                    }
                }
            }
        }
}

// ---------------------------------------------------------------------------
// Split-bf16 GEMM, 64x64 tile, BK=64 (R15): halves drain-barrier count on the
// two K=2048 shapes (qa N=768, kvfull N=576). LDS [2 ks][64][32] per array.
// ---------------------------------------------------------------------------
__global__ __launch_bounds__(256) void gemm_split64(
    const bf* __restrict__ Ah, const bf* __restrict__ Al,
    const bf* __restrict__ Bh, const bf* __restrict__ Bl,
    float* __restrict__ Cf, int M, int N, int K)
{
    __shared__ bf sAh[2 * 64 * 32], sAl[2 * 64 * 32];
    __shared__ bf sBh[2 * 64 * 32], sBl[2 * 64 * 32];

    const int tid = threadIdx.x;
    const int lane = tid & 63, wave = tid >> 6;
    const int row0 = blockIdx.y * 64, col0 = blockIdx.x * 64;
    const int wm = (wave & 1) * 32, wn = (wave >> 1) * 32;
    const int fr = lane & 15, quad = lane >> 4;

    f32x4 acc[2][2];
#pragma unroll
    for (int i = 0; i < 2; i++)
#pragma unroll
        for (int j = 0; j < 2; j++) acc[i][j] = (f32x4){0.f, 0.f, 0.f, 0.f};

    const int trow = tid >> 2;
    const int tcol = (tid & 3) * 8;
    const size_t ldsoff = (size_t)wave * 1024;

    for (int kt = 0; kt < K; kt += 64) {
        __syncthreads();
        GLOAD_LDS16(Ah + (size_t)(row0 + trow) * K + kt + tcol,      (char*)sAh + ldsoff);
        GLOAD_LDS16(Ah + (size_t)(row0 + trow) * K + kt + 32 + tcol, (char*)sAh + 4096 + ldsoff);
        GLOAD_LDS16(Al + (size_t)(row0 + trow) * K + kt + tcol,      (char*)sAl + ldsoff);
        GLOAD_LDS16(Al + (size_t)(row0 + trow) * K + kt + 32 + tcol, (char*)sAl + 4096 + ldsoff);
        GLOAD_LDS16(Bh + (size_t)(col0 + trow) * K + kt + tcol,      (char*)sBh + ldsoff);
        GLOAD_LDS16(Bh + (size_t)(col0 + trow) * K + kt + 32 + tcol, (char*)sBh + 4096 + ldsoff);
        GLOAD_LDS16(Bl + (size_t)(col0 + trow) * K + kt + tcol,      (char*)sBl + ldsoff);
        GLOAD_LDS16(Bl + (size_t)(col0 + trow) * K + kt + 32 + tcol, (char*)sBl + 4096 + ldsoff);
        __syncthreads();

#pragma unroll
        for (int ks = 0; ks < 2; ks++) {
            bf16x8 a_h[2], a_l[2], b_h[2], b_l[2];
#pragma unroll
            for (int mt = 0; mt < 2; mt++) {
                const int r = ks * 2048 + (wm + mt * 16 + fr) * 32 + quad * 8;
                a_h[mt] = *(const bf16x8*)&sAh[r];
                a_l[mt] = *(const bf16x8*)&sAl[r];
            }
#pragma unroll
            for (int nt = 0; nt < 2; nt++) {
                const int r = ks * 2048 + (wn + nt * 16 + fr) * 32 + quad * 8;
                b_h[nt] = *(const bf16x8*)&sBh[r];
                b_l[nt] = *(const bf16x8*)&sBl[r];
            }
#pragma unroll
            for (int mt = 0; mt < 2; mt++)
#pragma unroll
                for (int nt = 0; nt < 2; nt++) {
                    acc[mt][nt] = __builtin_amdgcn_mfma_f32_16x16x32_bf16(
                        a_l[mt], b_h[nt], acc[mt][nt], 0, 0, 0);
                    acc[mt][nt] = __builtin_amdgcn_mfma_f32_16x16x32_bf16(
                        a_h[mt], b_l[nt], acc[mt][nt], 0, 0, 0);
                    acc[mt][nt] = __builtin_amdgcn_mfma_f32_16x16x32_bf16(
                        a_h[mt], b_h[nt], acc[mt][nt], 0, 0, 0);
                }
        }
    }

#pragma unroll
    for (int mt = 0; mt < 2; mt++)
#pragma unroll
        for (int nt = 0; nt < 2; nt++)
#pragma unroll
            for (int r = 0; r < 4; r++)
                Cf[(size_t)(row0 + wm + mt * 16 + quad * 4 + r) * N +
                   col0 + wn + nt * 16 + fr] = acc[mt][nt][r];
}

// ---------------------------------------------------------------------------
// Plain bf16 GEMM (post-softmax out-projection): C = A @ B^T, single MFMA.
// BK=64 (R15): halves drain-barrier count (K=2048). LDS [2 ks][128][32]/array.
// ---------------------------------------------------------------------------
__global__ __launch_bounds__(256) void gemm_bf16(
    const bf* __restrict__ Ah, const bf* __restrict__ Bh,
    float* __restrict__ Cf, int M, int N, int K)
{
    __shared__ bf sAh[2 * 128 * 32];
    __shared__ bf sBh[2 * 128 * 32];

    const int tid = threadIdx.x;
    const int lane = tid & 63, wave = tid >> 6;
    const int row0 = blockIdx.y * 128, col0 = blockIdx.x * 128;
    const int wm = (wave & 1) * 64, wn = (wave >> 1) * 64;
    const int fr = lane & 15, quad = lane >> 4;

    f32x4 acc[4][4];
#pragma unroll
    for (int i = 0; i < 4; i++)
#pragma unroll
        for (int j = 0; j < 4; j++) acc[i][j] = (f32x4){0.f, 0.f, 0.f, 0.f};

    const int trow = tid >> 2;
    const int tcol = (tid & 3) * 8;
    const size_t ldsoff = (size_t)wave * 1024;

    for (int kt = 0; kt < K; kt += 64) {
        __syncthreads();
        GLOAD_LDS16(Ah + (size_t)(row0 + trow) * K + kt + tcol,           (char*)sAh + ldsoff);
        GLOAD_LDS16(Ah + (size_t)(row0 + 64 + trow) * K + kt + tcol,      (char*)sAh + 4096 + ldsoff);
        GLOAD_LDS16(Ah + (size_t)(row0 + trow) * K + kt + 32 + tcol,      (char*)sAh + 8192 + ldsoff);
        GLOAD_LDS16(Ah + (size_t)(row0 + 64 + trow) * K + kt + 32 + tcol, (char*)sAh + 12288 + ldsoff);
        GLOAD_LDS16(Bh + (size_t)(col0 + trow) * K + kt + tcol,           (char*)sBh + ldsoff);
        GLOAD_LDS16(Bh + (size_t)(col0 + 64 + trow) * K + kt + tcol,      (char*)sBh + 4096 + ldsoff);
        GLOAD_LDS16(Bh + (size_t)(col0 + trow) * K + kt + 32 + tcol,      (char*)sBh + 8192 + ldsoff);
        GLOAD_LDS16(Bh + (size_t)(col0 + 64 + trow) * K + kt + 32 + tcol, (char*)sBh + 12288 + ldsoff);
        __syncthreads();

#pragma unroll
        for (int ks = 0; ks < 2; ks++) {
            bf16x8 a_h[4], b_h[4];
#pragma unroll
            for (int mt = 0; mt < 4; mt++)
                a_h[mt] = *(const bf16x8*)&sAh[ks * 4096 + (wm + mt * 16 + fr) * 32 + quad * 8];
#pragma unroll
            for (int nt = 0; nt < 4; nt++)
                b_h[nt] = *(const bf16x8*)&sBh[ks * 4096 + (wn + nt * 16 + fr) * 32 + quad * 8];
#pragma unroll
            for (int mt = 0; mt < 4; mt++)
#pragma unroll
                for (int nt = 0; nt < 4; nt++)
                    acc[mt][nt] = __builtin_amdgcn_mfma_f32_16x16x32_bf16(
                        a_h[mt], b_h[nt], acc[mt][nt], 0, 0, 0);
        }
    }

#pragma unroll
    for (int mt = 0; mt < 4; mt++)
#pragma unroll
        for (int nt = 0; nt < 4; nt++)
#pragma unroll
            for (int r = 0; r < 4; r++)
                Cf[(size_t)(row0 + wm + mt * 16 + quad * 4 + r) * N +
                   col0 + wn + nt * 16 + fr] = acc[mt][nt][r];
}

// ---------------------------------------------------------------------------
// Monolithic MFMA flash attention (R9 fabric, R18 fat-chunk staging).
// 512 blocks = (h, qt), heavy/light paired, sequential k, R9 block mapping.
// Per 128-key k-tile: 3 chunks of 64 dims, single 48 KB buffer, pure drain
// (stage -> sync -> compute -> WAR sync). Expensive drains/tile: 5 (was 8).
// fp32 online softmax, PV with padded Ps (stride 72) + preloaded V pairs.
// LDS 60416 B (same as R9) -> 2 blocks/CU. Accumulation order identical.
// Buffer: Qh0@0 Qh1@4K Ql0@8K Ql1@12K | Kh@16K (2 sub x 8K) | Kl@32K (2 x 8K)
// sVt aliases smem[0:16K] during PV.
// ---------------------------------------------------------------------------
__global__ __launch_bounds__(256, 2) void attn_mfma(
    const bf* __restrict__ qh, const bf* __restrict__ ql,
    const bf* __restrict__ knh, const bf* __restrict__ knl,
    const bf* __restrict__ kpeh, const bf* __restrict__ kpel,
    const bf* __restrict__ vT, bf* __restrict__ yh)
{
    const int bid = blockIdx.x;
    const int h = bid & 15;
    const int qt = (bid < 256) ? (31 - (bid >> 4)) : ((bid - 256) >> 4);

    const int tid = threadIdx.x;
    const int lane = tid & 63, wave = tid >> 6;
    const int fr = lane & 15, quad = lane >> 4;
    const int wn = wave * 32;

    __shared__ __align__(16) char smem[60416];
    bf* Ps  = (bf*)(smem + 49152);
    float* redM = (float*)(smem + 58368); // [64][4]
    float* redS = (float*)(smem + 59392); // [64][4]

    float m_i[16], l_i[16], al[16];
    f32x4 O[4][2];
#pragma unroll
    for (int i = 0; i < 16; i++) { m_i[i] = -INFINITY; l_i[i] = 0.0f; }
#pragma unroll
    for (int mt = 0; mt < 4; mt++)
#pragma unroll
        for (int nt = 0; nt < 2; nt++) O[mt][nt] = (f32x4){0.f, 0.f, 0.f, 0.f};

    const int q0 = qt * 64;
    const int nkt = ((qt + 1) * 64 + 127) >> 7;
    const int trow = tid >> 2, tcol = (tid & 3) * 8;
    const size_t loff = (size_t)wave * 1024;

    for (int kt = 0; kt < nkt; kt++) {
        const int k0 = kt * 128;
        f32x4 S[4][2];
#pragma unroll
        for (int mt = 0; mt < 4; mt++)
#pragma unroll
            for (int nt = 0; nt < 2; nt++) S[mt][nt] = (f32x4){0.f, 0.f, 0.f, 0.f};

        // leading barrier: prior k-tile's PV readers of smem (sVt alias) done
        __syncthreads();

        // ---- S = Q.K^T over 192 dims: 3 fat chunks (64 dims), pure drain --
#pragma unroll
        for (int ch = 0; ch < 3; ch++) {
            const int d0 = ch * 64;
            // stage: 12 loads/thread (Q 4 + K 8), two 32-dim sub-chunks
#pragma unroll
            for (int s = 0; s < 2; s++) {
                const int ds = d0 + s * 32;
                GLOAD_LDS16(qh + ((size_t)(q0 + trow) * 16 + h) * 192 + ds + tcol,
                            smem + s * 4096 + loff);
                GLOAD_LDS16(ql + ((size_t)(q0 + trow) * 16 + h) * 192 + ds + tcol,
                            smem + 8192 + s * 4096 + loff);
                if (ds < 128) {
                    GLOAD_LDS16(knh + ((size_t)(k0 + trow) * 16 + h) * 128 + ds + tcol,
                                smem + 16384 + s * 8192 + loff);
                    GLOAD_LDS16(knh + ((size_t)(k0 + 64 + trow) * 16 + h) * 128 + ds + tcol,
                                smem + 16384 + s * 8192 + 4096 + loff);
                    GLOAD_LDS16(knl + ((size_t)(k0 + trow) * 16 + h) * 128 + ds + tcol,
                                smem + 32768 + s * 8192 + loff);
                    GLOAD_LDS16(knl + ((size_t)(k0 + 64 + trow) * 16 + h) * 128 + ds + tcol,
                                smem + 32768 + s * 8192 + 4096 + loff);
                } else {
                    GLOAD_LDS16(kpeh + (size_t)(k0 + trow) * 64 + (ds - 128) + tcol,
                                smem + 16384 + s * 8192 + loff);
                    GLOAD_LDS16(kpeh + (size_t)(k0 + 64 + trow) * 64 + (ds - 128) + tcol,
                                smem + 16384 + s * 8192 + 4096 + loff);
                    GLOAD_LDS16(kpel + (size_t)(k0 + trow) * 64 + (ds - 128) + tcol,
                                smem + 32768 + s * 8192 + loff);
                    GLOAD_LDS16(kpel + (size_t)(k0 + 64 + trow) * 64 + (ds - 128) + tcol,
                                smem + 32768 + s * 8192 + 4096 + loff);
                }
            }
            __syncthreads();   // drain: all 12 loads landed (convoy feedback)

#pragma unroll
            for (int s = 0; s < 2; s++) {
                const bf* sQh = (const bf*)(smem + s * 4096);
                const bf* sQl = (const bf*)(smem + 8192 + s * 4096);
                const bf* sKh = (const bf*)(smem + 16384 + s * 8192);
                const bf* sKl = (const bf*)(smem + 32768 + s * 8192);
                bf16x8 a_h[4], a_l[4], b_h[2], b_l[2];
#pragma unroll
                for (int mt = 0; mt < 4; mt++) {
                    const int r = (mt * 16 + fr) * 32 + quad * 8;
                    a_h[mt] = *(const bf16x8*)&sQh[r];
                    a_l[mt] = *(const bf16x8*)&sQl[r];
                }
#pragma unroll
                for (int nt = 0; nt < 2; nt++) {
                    const int r = (wn + nt * 16 + fr) * 32 + quad * 8;
                    b_h[nt] = *(const bf16x8*)&sKh[r];
                    b_l[nt] = *(const bf16x8*)&sKl[r];
                }
#pragma unroll
                for (int mt = 0; mt < 4; mt++)
#pragma unroll
                    for (int nt = 0; nt < 2; nt++) {
                        S[mt][nt] = __builtin_amdgcn_mfma_f32_16x16x32_bf16(
                            a_l[mt], b_h[nt], S[mt][nt], 0, 0, 0);
                        S[mt][nt] = __builtin_amdgcn_mfma_f32_16x16x32_bf16(
                            a_h[mt], b_l[nt], S[mt][nt], 0, 0, 0);
                        S[mt][nt] = __builtin_amdgcn_mfma_f32_16x16x32_bf16(
                            a_h[mt], b_h[nt], S[mt][nt], 0, 0, 0);
                    }
            }
            if (ch < 2) __syncthreads();   // WAR before next stage (vmcnt==0: cheap)
        }

        // ---- online softmax (fp32, block-wide row reductions) ----
#pragma unroll
        for (int mt = 0; mt < 4; mt++)
#pragma unroll
            for (int rr = 0; rr < 4; rr++) {
                const int ri = mt * 16 + quad * 4 + rr;
                const int rowg = q0 + ri;
                float v0 = S[mt][0][rr] * SOFTSCALE;
                float v1 = S[mt][1][rr] * SOFTSCALE;
                if (k0 + wn + fr > rowg)      v0 = -INFINITY;
                if (k0 + wn + 16 + fr > rowg) v1 = -INFINITY;
                S[mt][0][rr] = v0; S[mt][1][rr] = v1;
                float pm = fmaxf(v0, v1);
#pragma unroll
                for (int o = 1; o < 16; o <<= 1) pm = fmaxf(pm, __shfl_xor(pm, o, 64));
                if (fr == 0) redM[ri * 4 + wave] = pm;
            }
        __syncthreads();   // B1: redM visible; also last-chunk WAR vs V stage
#pragma unroll
        for (int mt = 0; mt < 4; mt++)
#pragma unroll
            for (int rr = 0; rr < 4; rr++) {
                const int idx = mt * 4 + rr;
                const int ri = mt * 16 + quad * 4 + rr;
                const float4 g = *(const float4*)&redM[ri * 4];
                const float gm = fmaxf(fmaxf(g.x, g.y), fmaxf(g.z, g.w));
                const float mn = fmaxf(m_i[idx], gm);
                al[idx] = __expf(m_i[idx] - mn);
                m_i[idx] = mn;
                const float p0 = __expf(S[mt][0][rr] - mn);
                const float p1 = __expf(S[mt][1][rr] - mn);
                S[mt][0][rr] = p0; S[mt][1][rr] = p1;   // keep p for PV store
                float ps = p0 + p1;
#pragma unroll
                for (int o = 1; o < 16; o <<= 1) ps += __shfl_xor(ps, o, 64);
                if (fr == 0) redS[ri * 4 + wave] = ps;
            }
#pragma unroll
        for (int mt = 0; mt < 4; mt++)
#pragma unroll
            for (int nt = 0; nt < 2; nt++)
#pragma unroll
                for (int rr = 0; rr < 4; rr++) O[mt][nt][rr] *= al[mt * 4 + rr];
        __syncthreads();   // B2: redS visible
#pragma unroll
        for (int mt = 0; mt < 4; mt++)
#pragma unroll
            for (int rr = 0; rr < 4; rr++) {
                const int idx = mt * 4 + rr;
                const int ri = mt * 16 + quad * 4 + rr;
                const float4 s4 = *(const float4*)&redS[ri * 4];
                l_i[idx] = l_i[idx] * al[idx] + (s4.x + s4.y + s4.z + s4.w);
            }

        // ---- PV: two 64-key halves; both 32-key V chunks preloaded ----
        bf* sVt = (bf*)smem;   // aliases buf (dead during PV)
#pragma unroll
        for (int half = 0; half < 2; half++) {
            if (half) __syncthreads();   // prior Ps/sVt readers done
            if ((wave >> 1) == half) {
                const int kc = wn - half * 64;   // 0 or 32
#pragma unroll
                for (int mt = 0; mt < 4; mt++)
#pragma unroll
                    for (int rr = 0; rr < 4; rr++) {
                        const int ri = mt * 16 + quad * 4 + rr;
                        Ps[ri * 72 + kc + fr]      = __float2bfloat16(S[mt][0][rr]);
                        Ps[ri * 72 + kc + 16 + fr] = __float2bfloat16(S[mt][1][rr]);
                    }
            }
            const int kb = k0 + half * 64;
            GLOAD_LDS16(vT + ((size_t)(h * 128 + trow)) * 2048 + kb + tcol,           (char*)sVt + loff);
            GLOAD_LDS16(vT + ((size_t)(h * 128 + 64 + trow)) * 2048 + kb + tcol,      (char*)sVt + 4096 + loff);
            GLOAD_LDS16(vT + ((size_t)(h * 128 + trow)) * 2048 + kb + 32 + tcol,      (char*)sVt + 8192 + loff);
            GLOAD_LDS16(vT + ((size_t)(h * 128 + 64 + trow)) * 2048 + kb + 32 + tcol, (char*)sVt + 12288 + loff);
            __syncthreads();
#pragma unroll
            for (int vc = 0; vc < 2; vc++) {
                bf16x8 ap[4], bv[2];
#pragma unroll
                for (int mt = 0; mt < 4; mt++)
                    ap[mt] = *(const bf16x8*)&Ps[(mt * 16 + fr) * 72 + vc * 32 + quad * 8];
#pragma unroll
                for (int nt = 0; nt < 2; nt++)
                    bv[nt] = *(const bf16x8*)&sVt[vc * 4096 + (wn + nt * 16 + fr) * 32 + quad * 8];
#pragma unroll
                for (int mt = 0; mt < 4; mt++)
#pragma unroll
                    for (int nt = 0; nt < 2; nt++)
                        O[mt][nt] = __builtin_amdgcn_mfma_f32_16x16x32_bf16(
                            ap[mt], bv[nt], O[mt][nt], 0, 0, 0);
            }
        }
    }

    // ---- epilogue: y = O / l (bf16) ----
#pragma unroll
    for (int mt = 0; mt < 4; mt++)
#pragma unroll
        for (int rr = 0; rr < 4; rr++) {
            const float inv = 1.0f / l_i[mt * 4 + rr];
            const int row = q0 + mt * 16 + quad * 4 + rr;
#pragma unroll
            for (int nt = 0; nt < 2; nt++)
                yh[((size_t)row * 16 + h) * 128 + wn + nt * 16 + fr] =
                    __float2bfloat16(O[mt][nt][rr] * inv);
        }
}

// ---------------------------------------------------------------------------
// Workspace (peak < 85 MB):
//  A  @0        : xh(8.39) xl(8.39) -> yh@0, vT@8.39
//  AR @16.78    : (16.78) GEMM temporaries -> woh
//  persistent   : qh@33.55 ql@46.14 knh@58.72 knl@67.11 vh@75.50
//                 kpeh@83.89 kpel@84.15
// ---------------------------------------------------------------------------
extern "C" void kernel_launch(void* const* d_in, const int* in_sizes, int n_in,
                              void* d_out, int out_size, void* d_ws, size_t ws_size,
                              hipStream_t stream)
{
    const float* x        = (const float*)d_in[0];
    const float* freqs    = (const float*)d_in[1];
    const float* wq_a     = (const float*)d_in[3];
    const float* q_norm_w = (const float*)d_in[4];
    const float* wq_b     = (const float*)d_in[5];
    const float* wkv_a    = (const float*)d_in[6];
    const float* kv_norm_w= (const float*)d_in[7];
    const float* wkv_b    = (const float*)d_in[8];
    const float* wo       = (const float*)d_in[9];
    float* out            = (float*)d_out;

    char* ws = (char*)d_ws;
    bf* xh = (bf*)(ws);
    bf* xl = (bf*)(ws + 8388608);
    bf* yh = (bf*)(ws);                   // after x dead
    bf* vT = (bf*)(ws + 8388608);         // after x dead
    char* AR = ws + 16777216;
    bf*    wah    = (bf*)(AR);
    bf*    wal    = (bf*)(AR + 3145728);
    float* qa     = (float*)(AR + 6291456);
    bf*    qah    = (bf*)(AR);
    bf*    qal    = (bf*)(AR + 3145728);
    bf*    wbh    = (bf*)(AR + 6291456);
    bf*    wbl    = (bf*)(AR + 11010048);
    bf*    kah    = (bf*)(AR);
    bf*    kal    = (bf*)(AR + 2359296);
    float* kvfull = (float*)(AR + 4718592);
    bf*    ckvh   = (bf*)(AR + 9437184);
    bf*    ckvl   = (bf*)(AR + 11534336);
    bf*    wvh    = (bf*)(AR);
    bf*    wvl    = (bf*)(AR + 4194304);
    bf*    woh    = (bf*)(AR);
    bf* qh   = (bf*)(ws + 33554432);
    bf* ql   = (bf*)(ws + 46137344);
    bf* knh  = (bf*)(ws + 58720256);
    bf* knl  = (bf*)(ws + 67108864);
    bf* vh   = (bf*)(ws + 75497472);
    bf* kpeh = (bf*)(ws + 83886080);
    bf* kpel = (bf*)(ws + 84148224);

    dim3 blk(256);

    cvt_split<<<4096, blk, 0, stream>>>(x, xh, xl, D_MODEL * D_MODEL);
    cvt_split<<<1536, blk, 0, stream>>>(wq_a, wah, wal, QLORA * D_MODEL);
    gemm_split64<<<dim3(12, 32), blk, 0, stream>>>(
        xh, xl, wah, wal, qa, T_DIM, QLORA, D_MODEL);
    rmsnorm_cvt<<<T_DIM, blk, 0, stream>>>(qa, QLORA, QLORA, q_norm_w, qah, qal);
    cvt_split<<<2304, blk, 0, stream>>>(wq_b, wbh, wbl, 3072 * QLORA);
    gemm_split<1><<<dim3(24, 16), blk, 0, stream>>>(
        qah, qal, wbh, wbl, freqs, nullptr, qh, ql, nullptr,
        T_DIM, 3072, QLORA);
    cvt_split<<<1152, blk, 0, stream>>>(wkv_a, kah, kal, KVFULL_D * D_MODEL);
    gemm_split64<<<dim3(9, 32), blk, 0, stream>>>(
        xh, xl, kah, kal, kvfull, T_DIM, KVFULL_D, D_MODEL);
    rope_k_cvt<<<256, blk, 0, stream>>>(kvfull, freqs, kpeh, kpel);
    rmsnorm_cvt<<<T_DIM, blk, 0, stream>>>(kvfull, KVFULL_D, KVLORA, kv_norm_w, ckvh, ckvl);
    cvt_split<<<2048, blk, 0, stream>>>(wkv_b, wvh, wvl, 4096 * KVLORA);
    gemm_split<2><<<dim3(32, 16), blk, 0, stream>>>(
        ckvh, ckvl, wvh, wvl, nullptr, nullptr, knh, knl, vh,
        T_DIM, 4096, KVLORA);
    transpose_v<<<dim3(64, 4, 16), blk, 0, stream>>>(vh, vT);
    attn_mfma<<<dim3(512), blk, 0, stream>>>(
        qh, ql, knh, knl, kpeh, kpel, vT, yh);
    cvt_hi<<<4096, blk, 0, stream>>>(wo, woh, D_MODEL * D_MODEL);
    gemm_bf16<<<dim3(16, 16), blk, 0, stream>>>(
        yh, woh, out, T_DIM, D_MODEL, D_MODEL);
}

// Round 10
// 622.352 us; speedup vs baseline: 1.1301x; 1.0882x over previous
//
#include <hip/hip_runtime.h>
#include <hip/hip_bf16.h>
#include <math.h>

// ---------------------------------------------------------------------------
// DeepSeek MLA forward. Round 19:
//  - R18 post-mortem: fat-chunk attn staging FALSIFIED (FETCH 122->171 MB,
//    dur 265->318). Fourth confirmation: ANY deviation from R9's exact
//    load-issue cadence costs 1.4-3x FETCH. attn reverted to R15-exact,
//    frozen permanently. All further work is GEMM-side.
//  - R19: BK 32->64 for the remaining two GEMMs (gemm_split<1> wq_b K=768,
//    gemm_split<2> wkv_b K=512) — same drain-amortization R15 proved on the
//    K=2048 GEMMs (+22 us). Accumulation order bitwise identical (ks loop
//    walks the same 32-dim sub-chunks in order). LDS 32->64 KB -> 2
//    blocks/CU by LDS (not binding: grids 384/512 on 256 CUs).
//  - Everything else byte-identical to R15.
// ---------------------------------------------------------------------------

#define T_DIM 2048
#define HEADS 16
#define D_MODEL 2048
#define NOPE_D 128
#define ROPE_D 64
#define QKD_D 192
#define VD_D 128
#define QLORA 768
#define KVLORA 512
#define KVFULL_D 576
#define SOFTSCALE -96.0f
#define EPS_RMS 1e-6f

typedef __hip_bfloat16 bf;
typedef __attribute__((ext_vector_type(8))) short bf16x8;
typedef __attribute__((ext_vector_type(4))) float f32x4;

#define GLOAD_LDS16(gptr, lptr)                                               \
    __builtin_amdgcn_global_load_lds(                                         \
        (const __attribute__((address_space(1))) unsigned int*)(gptr),        \
        (__attribute__((address_space(3))) unsigned int*)(lptr), 16, 0, 0)

__device__ __forceinline__ void split2(float v, bf* hi, bf* lo) {
    bf h = __float2bfloat16(v);
    *hi = h;
    *lo = __float2bfloat16(v - __bfloat162float(h));
}

// ---------------------------------------------------------------------------
__global__ __launch_bounds__(256) void cvt_split(
    const float* __restrict__ in, bf* __restrict__ hi, bf* __restrict__ lo, int n)
{
    const int i = (blockIdx.x * 256 + threadIdx.x) * 4;
    if (i >= n) return;
    float4 v = *(const float4*)&in[i];
    float vv[4] = {v.x, v.y, v.z, v.w};
#pragma unroll
    for (int u = 0; u < 4; u++) split2(vv[u], &hi[i + u], &lo[i + u]);
}

__global__ __launch_bounds__(256) void cvt_hi(
    const float* __restrict__ in, bf* __restrict__ hi, int n)
{
    const int i = (blockIdx.x * 256 + threadIdx.x) * 4;
    if (i >= n) return;
    float4 v = *(const float4*)&in[i];
    hi[i + 0] = __float2bfloat16(v.x);
    hi[i + 1] = __float2bfloat16(v.y);
    hi[i + 2] = __float2bfloat16(v.z);
    hi[i + 3] = __float2bfloat16(v.w);
}

// ---------------------------------------------------------------------------
__global__ __launch_bounds__(256) void rmsnorm_cvt(
    const float* __restrict__ in, int ld, int D, const float* __restrict__ w,
    bf* __restrict__ hi, bf* __restrict__ lo)
{
    const int row = blockIdx.x;
    const float* r = in + (size_t)row * ld;
    float ss = 0.0f;
    for (int i = threadIdx.x; i < D; i += 256) { float v = r[i]; ss += v * v; }
#pragma unroll
    for (int o = 32; o > 0; o >>= 1) ss += __shfl_down(ss, o, 64);
    __shared__ float red[4];
    if ((threadIdx.x & 63) == 0) red[threadIdx.x >> 6] = ss;
    __syncthreads();
    ss = red[0] + red[1] + red[2] + red[3];
    const float scale = rsqrtf(ss / (float)D + EPS_RMS);
    for (int i = threadIdx.x; i < D; i += 256) {
        const float v = r[i] * scale * w[i];
        split2(v, &hi[(size_t)row * D + i], &lo[(size_t)row * D + i]);
    }
}

// ---------------------------------------------------------------------------
__global__ __launch_bounds__(256) void rope_k_cvt(
    const float* __restrict__ kvfull, const float* __restrict__ freqs,
    bf* __restrict__ kpeh, bf* __restrict__ kpel)
{
    const int idx = blockIdx.x * 256 + threadIdx.x;   // 65536
    const int i = idx & 31, t = idx >> 5;
    const float f = freqs[t * 32 + i];
    float sn, cs; sincosf(f, &sn, &cs);
    const float x1 = kvfull[(size_t)t * KVFULL_D + KVLORA + 2 * i];
    const float x2 = kvfull[(size_t)t * KVFULL_D + KVLORA + 2 * i + 1];
    split2(x1 * cs - x2 * sn, &kpeh[t * 64 + 2 * i], &kpel[t * 64 + 2 * i]);
    split2(x1 * sn + x2 * cs, &kpeh[t * 64 + 2 * i + 1], &kpel[t * 64 + 2 * i + 1]);
}

// ---------------------------------------------------------------------------
__global__ __launch_bounds__(256) void transpose_v(
    const bf* __restrict__ vh, bf* __restrict__ vT)
{
    __shared__ bf s[32][33];
    const int t0 = blockIdx.x * 32, d0 = blockIdx.y * 32, h = blockIdx.z;
    const int tid = threadIdx.x;
    const int i = tid >> 3, j0 = (tid & 7) * 4;
    const bf* src = vh + ((size_t)(t0 + i) * 16 + h) * 128 + d0 + j0;
#pragma unroll
    for (int u = 0; u < 4; u++) s[i][j0 + u] = src[u];
    __syncthreads();
    const int jj = tid >> 3, i0 = (tid & 7) * 4;
    bf* dst = vT + ((size_t)h * 128 + d0 + jj) * 2048 + t0 + i0;
#pragma unroll
    for (int u = 0; u < 4; u++) dst[u] = s[i0 + u][jj];
}

// ---------------------------------------------------------------------------
// Split-bf16 GEMM (score path), 128x128 tile, 3 MFMAs, BK=64 (R19).
// MODE 1: RoPE on d>=128 + split -> Oh/Ol (q). MODE 2: kn/v split write.
// LDS per array [2 ks][128][32] = 16 KB (64 KB total). Accumulation order
// identical to BK=32 (ks walks 32-dim sub-chunks in sequence).
// ---------------------------------------------------------------------------
template <int MODE>
__global__ __launch_bounds__(256) void gemm_split(
    const bf* __restrict__ Ah, const bf* __restrict__ Al,
    const bf* __restrict__ Bh, const bf* __restrict__ Bl,
    const float* __restrict__ freqs,
    float* __restrict__ Cf, bf* __restrict__ Oh, bf* __restrict__ Ol,
    bf* __restrict__ O2, int M, int N, int K)
{
    __shared__ bf sAh[2 * 128 * 32], sAl[2 * 128 * 32];
    __shared__ bf sBh[2 * 128 * 32], sBl[2 * 128 * 32];

    const int tid = threadIdx.x;
    const int lane = tid & 63, wave = tid >> 6;
    const int row0 = blockIdx.y * 128, col0 = blockIdx.x * 128;
    const int wm = (wave & 1) * 64, wn = (wave >> 1) * 64;
    const int fr = lane & 15, quad = lane >> 4;

    f32x4 acc[4][4];
#pragma unroll
    for (int i = 0; i < 4; i++)
#pragma unroll
        for (int j = 0; j < 4; j++) acc[i][j] = (f32x4){0.f, 0.f, 0.f, 0.f};

    const int trow = tid >> 2;
    const int tcol = (tid & 3) * 8;
    const size_t ldsoff = (size_t)wave * 1024;

    for (int kt = 0; kt < K; kt += 64) {
        __syncthreads();
#pragma unroll
        for (int ks = 0; ks < 2; ks++) {
            const int kk = kt + ks * 32;
            GLOAD_LDS16(Ah + (size_t)(row0 + trow) * K + kk + tcol,      (char*)sAh + ks * 8192 + ldsoff);
            GLOAD_LDS16(Ah + (size_t)(row0 + 64 + trow) * K + kk + tcol, (char*)sAh + ks * 8192 + 4096 + ldsoff);
            GLOAD_LDS16(Al + (size_t)(row0 + trow) * K + kk + tcol,      (char*)sAl + ks * 8192 + ldsoff);
            GLOAD_LDS16(Al + (size_t)(row0 + 64 + trow) * K + kk + tcol, (char*)sAl + ks * 8192 + 4096 + ldsoff);
            GLOAD_LDS16(Bh + (size_t)(col0 + trow) * K + kk + tcol,      (char*)sBh + ks * 8192 + ldsoff);
            GLOAD_LDS16(Bh + (size_t)(col0 + 64 + trow) * K + kk + tcol, (char*)sBh + ks * 8192 + 4096 + ldsoff);
            GLOAD_LDS16(Bl + (size_t)(col0 + trow) * K + kk + tcol,      (char*)sBl + ks * 8192 + ldsoff);
            GLOAD_LDS16(Bl + (size_t)(col0 + 64 + trow) * K + kk + tcol, (char*)sBl + ks * 8192 + 4096 + ldsoff);
        }
        __syncthreads();

#pragma unroll
        for (int ks = 0; ks < 2; ks++) {
            bf16x8 a_h[4], a_l[4], b_h[4], b_l[4];
#pragma unroll
            for (int mt = 0; mt < 4; mt++) {
                const int r = ks * 4096 + (wm + mt * 16 + fr) * 32 + quad * 8;
                a_h[mt] = *(const bf16x8*)&sAh[r];
                a_l[mt] = *(const bf16x8*)&sAl[r];
            }
#pragma unroll
            for (int nt = 0; nt < 4; nt++) {
                const int r = ks * 4096 + (wn + nt * 16 + fr) * 32 + quad * 8;
                b_h[nt] = *(const bf16x8*)&sBh[r];
                b_l[nt] = *(const bf16x8*)&sBl[r];
            }
#pragma unroll
            for (int mt = 0; mt < 4; mt++)
#pragma unroll
                for (int nt = 0; nt < 4; nt++) {
                    acc[mt][nt] = __builtin_amdgcn_mfma_f32_16x16x32_bf16(
                        a_l[mt], b_h[nt], acc[mt][nt], 0, 0, 0);
                    acc[mt][nt] = __builtin_amdgcn_mfma_f32_16x16x32_bf16(
                        a_h[mt], b_l[nt], acc[mt][nt], 0, 0, 0);
                    acc[mt][nt] = __builtin_amdgcn_mfma_f32_16x16x32_bf16(
                        a_h[mt], b_h[nt], acc[mt][nt], 0, 0, 0);
                }
        }
    }

#pragma unroll
    for (int mt = 0; mt < 4; mt++)
#pragma unroll
        for (int nt = 0; nt < 4; nt++) {
            const int colb = col0 + wn + nt * 16;
            const int col = colb + fr;
            if (MODE == 1) {
                const int d0 = colb % 192;
                const bool rope = (d0 >= 128);
                const int ii = (d0 + fr - 128) >> 1;
#pragma unroll
                for (int r = 0; r < 4; r++) {
                    const int row = row0 + wm + mt * 16 + quad * 4 + r;
                    float v = acc[mt][nt][r];
                    if (rope) {
                        const float other = __shfl_xor(v, 1);
                        float sn, cs; sincosf(freqs[row * 32 + ii], &sn, &cs);
                        v = (fr & 1) ? (other * sn + v * cs) : (v * cs - other * sn);
                    }
                    bf h8, l8; split2(v, &h8, &l8);
                    Oh[(size_t)row * N + col] = h8;
                    Ol[(size_t)row * N + col] = l8;
                }
            } else {
                const int hh = col >> 8;
                const int d = col & 255;
#pragma unroll
                for (int r = 0; r < 4; r++) {
                    const int row = row0 + wm + mt * 16 + quad * 4 + r;
                    const float v = acc[mt][nt][r];
                    if (d < 128) {
                        bf h8, l8; split2(v, &h8, &l8);
                        Oh[(size_t)row * 2048 + hh * 128 + d] = h8;
                        Ol[(size_t)row * 2048 + hh * 128 + d] = l8;
                    } else {
                        O2[(size_t)row * 2048 + hh * 128 + (d - 128)] = __float2bfloat16(v);
                    }
                }
            }
        }
}

// ---------------------------------------------------------------------------
// Split-bf16 GEMM, 64x64 tile, BK=64 (R15): halves drain-barrier count on the
// two K=2048 shapes (qa N=768, kvfull N=576). LDS [2 ks][64][32] per array.
// ---------------------------------------------------------------------------
__global__ __launch_bounds__(256) void gemm_split64(
    const bf* __restrict__ Ah, const bf* __restrict__ Al,
    const bf* __restrict__ Bh, const bf* __restrict__ Bl,
    float* __restrict__ Cf, int M, int N, int K)
{
    __shared__ bf sAh[2 * 64 * 32], sAl[2 * 64 * 32];
    __shared__ bf sBh[2 * 64 * 32], sBl[2 * 64 * 32];

    const int tid = threadIdx.x;
    const int lane = tid & 63, wave = tid >> 6;
    const int row0 = blockIdx.y * 64, col0 = blockIdx.x * 64;
    const int wm = (wave & 1) * 32, wn = (wave >> 1) * 32;
    const int fr = lane & 15, quad = lane >> 4;

    f32x4 acc[2][2];
#pragma unroll
    for (int i = 0; i < 2; i++)
#pragma unroll
        for (int j = 0; j < 2; j++) acc[i][j] = (f32x4){0.f, 0.f, 0.f, 0.f};

    const int trow = tid >> 2;
    const int tcol = (tid & 3) * 8;
    const size_t ldsoff = (size_t)wave * 1024;

    for (int kt = 0; kt < K; kt += 64) {
        __syncthreads();
        GLOAD_LDS16(Ah + (size_t)(row0 + trow) * K + kt + tcol,      (char*)sAh + ldsoff);
        GLOAD_LDS16(Ah + (size_t)(row0 + trow) * K + kt + 32 + tcol, (char*)sAh + 4096 + ldsoff);
        GLOAD_LDS16(Al + (size_t)(row0 + trow) * K + kt + tcol,      (char*)sAl + ldsoff);
        GLOAD_LDS16(Al + (size_t)(row0 + trow) * K + kt + 32 + tcol, (char*)sAl + 4096 + ldsoff);
        GLOAD_LDS16(Bh + (size_t)(col0 + trow) * K + kt + tcol,      (char*)sBh + ldsoff);
        GLOAD_LDS16(Bh + (size_t)(col0 + trow) * K + kt + 32 + tcol, (char*)sBh + 4096 + ldsoff);
        GLOAD_LDS16(Bl + (size_t)(col0 + trow) * K + kt + tcol,      (char*)sBl + ldsoff);
        GLOAD_LDS16(Bl + (size_t)(col0 + trow) * K + kt + 32 + tcol, (char*)sBl + 4096 + ldsoff);
        __syncthreads();

#pragma unroll
        for (int ks = 0; ks < 2; ks++) {
            bf16x8 a_h[2], a_l[2], b_h[2], b_l[2];
#pragma unroll
            for (int mt = 0; mt < 2; mt++) {
                const int r = ks * 2048 + (wm + mt * 16 + fr) * 32 + quad * 8;
                a_h[mt] = *(const bf16x8*)&sAh[r];
                a_l[mt] = *(const bf16x8*)&sAl[r];
            }
#pragma unroll
            for (int nt = 0; nt < 2; nt++) {
                const int r = ks * 2048 + (wn + nt * 16 + fr) * 32 + quad * 8;
                b_h[nt] = *(const bf16x8*)&sBh[r];
                b_l[nt] = *(const bf16x8*)&sBl[r];
            }
#pragma unroll
            for (int mt = 0; mt < 2; mt++)
#pragma unroll
                for (int nt = 0; nt < 2; nt++) {
                    acc[mt][nt] = __builtin_amdgcn_mfma_f32_16x16x32_bf16(
                        a_l[mt], b_h[nt], acc[mt][nt], 0, 0, 0);
                    acc[mt][nt] = __builtin_amdgcn_mfma_f32_16x16x32_bf16(
                        a_h[mt], b_l[nt], acc[mt][nt], 0, 0, 0);
                    acc[mt][nt] = __builtin_amdgcn_mfma_f32_16x16x32_bf16(
                        a_h[mt], b_h[nt], acc[mt][nt], 0, 0, 0);
                }
        }
    }

#pragma unroll
    for (int mt = 0; mt < 2; mt++)
#pragma unroll
        for (int nt = 0; nt < 2; nt++)
#pragma unroll
            for (int r = 0; r < 4; r++)
                Cf[(size_t)(row0 + wm + mt * 16 + quad * 4 + r) * N +
                   col0 + wn + nt * 16 + fr] = acc[mt][nt][r];
}

// ---------------------------------------------------------------------------
// Plain bf16 GEMM (post-softmax out-projection): C = A @ B^T, single MFMA.
// BK=64 (R15): halves drain-barrier count (K=2048). LDS [2 ks][128][32]/array.
// ---------------------------------------------------------------------------
__global__ __launch_bounds__(256) void gemm_bf16(
    const bf* __restrict__ Ah, const bf* __restrict__ Bh,
    float* __restrict__ Cf, int M, int N, int K)
{
    __shared__ bf sAh[2 * 128 * 32];
    __shared__ bf sBh[2 * 128 * 32];

    const int tid = threadIdx.x;
    const int lane = tid & 63, wave = tid >> 6;
    const int row0 = blockIdx.y * 128, col0 = blockIdx.x * 128;
    const int wm = (wave & 1) * 64, wn = (wave >> 1) * 64;
    const int fr = lane & 15, quad = lane >> 4;

    f32x4 acc[4][4];
#pragma unroll
    for (int i = 0; i < 4; i++)
#pragma unroll
        for (int j = 0; j < 4; j++) acc[i][j] = (f32x4){0.f, 0.f, 0.f, 0.f};

    const int trow = tid >> 2;
    const int tcol = (tid & 3) * 8;
    const size_t ldsoff = (size_t)wave * 1024;

    for (int kt = 0; kt < K; kt += 64) {
        __syncthreads();
        GLOAD_LDS16(Ah + (size_t)(row0 + trow) * K + kt + tcol,           (char*)sAh + ldsoff);
        GLOAD_LDS16(Ah + (size_t)(row0 + 64 + trow) * K + kt + tcol,      (char*)sAh + 4096 + ldsoff);
        GLOAD_LDS16(Ah + (size_t)(row0 + trow) * K + kt + 32 + tcol,      (char*)sAh + 8192 + ldsoff);
        GLOAD_LDS16(Ah + (size_t)(row0 + 64 + trow) * K + kt + 32 + tcol, (char*)sAh + 12288 + ldsoff);
        GLOAD_LDS16(Bh + (size_t)(col0 + trow) * K + kt + tcol,           (char*)sBh + ldsoff);
        GLOAD_LDS16(Bh + (size_t)(col0 + 64 + trow) * K + kt + tcol,      (char*)sBh + 4096 + ldsoff);
        GLOAD_LDS16(Bh + (size_t)(col0 + trow) * K + kt + 32 + tcol,      (char*)sBh + 8192 + ldsoff);
        GLOAD_LDS16(Bh + (size_t)(col0 + 64 + trow) * K + kt + 32 + tcol, (char*)sBh + 12288 + ldsoff);
        __syncthreads();

#pragma unroll
        for (int ks = 0; ks < 2; ks++) {
            bf16x8 a_h[4], b_h[4];
#pragma unroll
            for (int mt = 0; mt < 4; mt++)
                a_h[mt] = *(const bf16x8*)&sAh[ks * 4096 + (wm + mt * 16 + fr) * 32 + quad * 8];
#pragma unroll
            for (int nt = 0; nt < 4; nt++)
                b_h[nt] = *(const bf16x8*)&sBh[ks * 4096 + (wn + nt * 16 + fr) * 32 + quad * 8];
#pragma unroll
            for (int mt = 0; mt < 4; mt++)
#pragma unroll
                for (int nt = 0; nt < 4; nt++)
                    acc[mt][nt] = __builtin_amdgcn_mfma_f32_16x16x32_bf16(
                        a_h[mt], b_h[nt], acc[mt][nt], 0, 0, 0);
        }
    }

#pragma unroll
    for (int mt = 0; mt < 4; mt++)
#pragma unroll
        for (int nt = 0; nt < 4; nt++)
#pragma unroll
            for (int r = 0; r < 4; r++)
                Cf[(size_t)(row0 + wm + mt * 16 + quad * 4 + r) * N +
                   col0 + wn + nt * 16 + fr] = acc[mt][nt][r];
}

// ---------------------------------------------------------------------------
// Monolithic MFMA flash attention (EXACT R9/R15 revert — FROZEN).
// 512 blocks = (h, qt), heavy/light paired. Per 128-key k-tile: ping-pong
// staged S (6 chunks x 1 barrier), fp32 online softmax, PV with padded Ps
// (stride 72) + preloaded V pairs. LDS 60.4 KB -> 2 blocks/CU. (256,2).
// Do NOT restructure: R10-R14, R16-R18 all degraded FETCH 1.4-3x.
// ---------------------------------------------------------------------------
__global__ __launch_bounds__(256, 2) void attn_mfma(
    const bf* __restrict__ qh, const bf* __restrict__ ql,
    const bf* __restrict__ knh, const bf* __restrict__ knl,
    const bf* __restrict__ kpeh, const bf* __restrict__ kpel,
    const bf* __restrict__ vT, bf* __restrict__ yh)
{
    const int bid = blockIdx.x;
    const int h = bid & 15;
    const int qt = (bid < 256) ? (31 - (bid >> 4)) : ((bid - 256) >> 4);

    const int tid = threadIdx.x;
    const int lane = tid & 63, wave = tid >> 6;
    const int fr = lane & 15, quad = lane >> 4;
    const int wn = wave * 32;

    // buf0 @0, buf1 @24576 (each: Qh 0 / Ql 4096 / Kh 8192 / Kl 16384)
    // sVt aliases buf0[0:16384] during PV. Ps @49152 ([64][72] bf16).
    __shared__ __align__(16) char smem[60416];
    bf* Ps  = (bf*)(smem + 49152);
    float* redM = (float*)(smem + 58368); // [64][4]
    float* redS = (float*)(smem + 59392); // [64][4]

    float m_i[16], l_i[16], al[16];
    f32x4 O[4][2];
#pragma unroll
    for (int i = 0; i < 16; i++) { m_i[i] = -INFINITY; l_i[i] = 0.0f; }
#pragma unroll
    for (int mt = 0; mt < 4; mt++)
#pragma unroll
        for (int nt = 0; nt < 2; nt++) O[mt][nt] = (f32x4){0.f, 0.f, 0.f, 0.f};

    const int q0 = qt * 64;
    const int nkt = ((qt + 1) * 64 + 127) >> 7;
    const int trow = tid >> 2, tcol = (tid & 3) * 8;
    const size_t loff = (size_t)wave * 1024;

    for (int kt = 0; kt < nkt; kt++) {
        const int k0 = kt * 128;
        f32x4 S[4][2];
#pragma unroll
        for (int mt = 0; mt < 4; mt++)
#pragma unroll
            for (int nt = 0; nt < 2; nt++) S[mt][nt] = (f32x4){0.f, 0.f, 0.f, 0.f};

        // leading barrier: prior k-tile's PV readers of buf0 (sVt alias) done
        __syncthreads();

        // ---- S = Q.K^T over 192 dims: 6 chunks, ping-pong, 1 barrier each --
        for (int ch = 0; ch < 6; ch++) {
            const int d0 = ch * 32;
            char* buf = smem + ((ch & 1) ? 24576 : 0);
            GLOAD_LDS16(qh + ((size_t)(q0 + trow) * 16 + h) * 192 + d0 + tcol, buf + loff);
            GLOAD_LDS16(ql + ((size_t)(q0 + trow) * 16 + h) * 192 + d0 + tcol, buf + 4096 + loff);
            if (d0 < 128) {
                GLOAD_LDS16(knh + ((size_t)(k0 + trow) * 16 + h) * 128 + d0 + tcol,      buf + 8192 + loff);
                GLOAD_LDS16(knh + ((size_t)(k0 + 64 + trow) * 16 + h) * 128 + d0 + tcol, buf + 12288 + loff);
                GLOAD_LDS16(knl + ((size_t)(k0 + trow) * 16 + h) * 128 + d0 + tcol,      buf + 16384 + loff);
                GLOAD_LDS16(knl + ((size_t)(k0 + 64 + trow) * 16 + h) * 128 + d0 + tcol, buf + 20480 + loff);
            } else {
                GLOAD_LDS16(kpeh + (size_t)(k0 + trow) * 64 + (d0 - 128) + tcol,      buf + 8192 + loff);
                GLOAD_LDS16(kpeh + (size_t)(k0 + 64 + trow) * 64 + (d0 - 128) + tcol, buf + 12288 + loff);
                GLOAD_LDS16(kpel + (size_t)(k0 + trow) * 64 + (d0 - 128) + tcol,      buf + 16384 + loff);
                GLOAD_LDS16(kpel + (size_t)(k0 + 64 + trow) * 64 + (d0 - 128) + tcol, buf + 20480 + loff);
            }
            __syncthreads();

            const bf* sQh = (const bf*)buf;
            const bf* sQl = (const bf*)(buf + 4096);
            const bf* sKh = (const bf*)(buf + 8192);
            const bf* sKl = (const bf*)(buf + 16384);
            bf16x8 a_h[4], a_l[4], b_h[2], b_l[2];
#pragma unroll
            for (int mt = 0; mt < 4; mt++) {
                const int r = (mt * 16 + fr) * 32 + quad * 8;
                a_h[mt] = *(const bf16x8*)&sQh[r];
                a_l[mt] = *(const bf16x8*)&sQl[r];
            }
#pragma unroll
            for (int nt = 0; nt < 2; nt++) {
                const int r = (wn + nt * 16 + fr) * 32 + quad * 8;
                b_h[nt] = *(const bf16x8*)&sKh[r];
                b_l[nt] = *(const bf16x8*)&sKl[r];
            }
#pragma unroll
            for (int mt = 0; mt < 4; mt++)
#pragma unroll
                for (int nt = 0; nt < 2; nt++) {
                    S[mt][nt] = __builtin_amdgcn_mfma_f32_16x16x32_bf16(
                        a_l[mt], b_h[nt], S[mt][nt], 0, 0, 0);
                    S[mt][nt] = __builtin_amdgcn_mfma_f32_16x16x32_bf16(
                        a_h[mt], b_l[nt], S[mt][nt], 0, 0, 0);
                    S[mt][nt] = __builtin_amdgcn_mfma_f32_16x16x32_bf16(
                        a_h[mt], b_h[nt], S[mt][nt], 0, 0, 0);
                }
        }

        // ---- online softmax (fp32, block-wide row reductions) ----
#pragma unroll
        for (int mt = 0; mt < 4; mt++)
#pragma unroll
            for (int rr = 0; rr < 4; rr++) {
                const int ri = mt * 16 + quad * 4 + rr;
                const int rowg = q0 + ri;
                float v0 = S[mt][0][rr] * SOFTSCALE;
                float v1 = S[mt][1][rr] * SOFTSCALE;
                if (k0 + wn + fr > rowg)      v0 = -INFINITY;
                if (k0 + wn + 16 + fr > rowg) v1 = -INFINITY;
                S[mt][0][rr] = v0; S[mt][1][rr] = v1;
                float pm = fmaxf(v0, v1);
#pragma unroll
                for (int o = 1; o < 16; o <<= 1) pm = fmaxf(pm, __shfl_xor(pm, o, 64));
                if (fr == 0) redM[ri * 4 + wave] = pm;
            }
        __syncthreads();
#pragma unroll
        for (int mt = 0; mt < 4; mt++)
#pragma unroll
            for (int rr = 0; rr < 4; rr++) {
                const int idx = mt * 4 + rr;
                const int ri = mt * 16 + quad * 4 + rr;
                const float4 g = *(const float4*)&redM[ri * 4];
                const float gm = fmaxf(fmaxf(g.x, g.y), fmaxf(g.z, g.w));
                const float mn = fmaxf(m_i[idx], gm);
                al[idx] = __expf(m_i[idx] - mn);
                m_i[idx] = mn;
                const float p0 = __expf(S[mt][0][rr] - mn);
                const float p1 = __expf(S[mt][1][rr] - mn);
                S[mt][0][rr] = p0; S[mt][1][rr] = p1;   // keep p for PV store
                float ps = p0 + p1;
#pragma unroll
                for (int o = 1; o < 16; o <<= 1) ps += __shfl_xor(ps, o, 64);
                if (fr == 0) redS[ri * 4 + wave] = ps;
            }
#pragma unroll
        for (int mt = 0; mt < 4; mt++)
#pragma unroll
            for (int nt = 0; nt < 2; nt++)
#pragma unroll
                for (int rr = 0; rr < 4; rr++) O[mt][nt][rr] *= al[mt * 4 + rr];
        __syncthreads();
#pragma unroll
        for (int mt = 0; mt < 4; mt++)
#pragma unroll
            for (int rr = 0; rr < 4; rr++) {
                const int idx = mt * 4 + rr;
                const int ri = mt * 16 + quad * 4 + rr;
                const float4 s4 = *(const float4*)&redS[ri * 4];
                l_i[idx] = l_i[idx] * al[idx] + (s4.x + s4.y + s4.z + s4.w);
            }

        // ---- PV: two 64-key halves; both 32-key V chunks preloaded ----
        bf* sVt = (bf*)smem;   // aliases buf0 (dead during PV)
#pragma unroll
        for (int half = 0; half < 2; half++) {
            if (half) __syncthreads();   // prior Ps/sVt readers done
            if ((wave >> 1) == half) {
                const int kc = wn - half * 64;   // 0 or 32
#pragma unroll
                for (int mt = 0; mt < 4; mt++)
#pragma unroll
                    for (int rr = 0; rr < 4; rr++) {
                        const int ri = mt * 16 + quad * 4 + rr;
                        Ps[ri * 72 + kc + fr]      = __float2bfloat16(S[mt][0][rr]);
                        Ps[ri * 72 + kc + 16 + fr] = __float2bfloat16(S[mt][1][rr]);
                    }
            }
            const int kb = k0 + half * 64;
            GLOAD_LDS16(vT + ((size_t)(h * 128 + trow)) * 2048 + kb + tcol,           (char*)sVt + loff);
            GLOAD_LDS16(vT + ((size_t)(h * 128 + 64 + trow)) * 2048 + kb + tcol,      (char*)sVt + 4096 + loff);
            GLOAD_LDS16(vT + ((size_t)(h * 128 + trow)) * 2048 + kb + 32 + tcol,      (char*)sVt + 8192 + loff);
            GLOAD_LDS16(vT + ((size_t)(h * 128 + 64 + trow)) * 2048 + kb + 32 + tcol, (char*)sVt + 12288 + loff);
            __syncthreads();
#pragma unroll
            for (int vc = 0; vc < 2; vc++) {
                bf16x8 ap[4], bv[2];
#pragma unroll
                for (int mt = 0; mt < 4; mt++)
                    ap[mt] = *(const bf16x8*)&Ps[(mt * 16 + fr) * 72 + vc * 32 + quad * 8];
#pragma unroll
                for (int nt = 0; nt < 2; nt++)
                    bv[nt] = *(const bf16x8*)&sVt[vc * 4096 + (wn + nt * 16 + fr) * 32 + quad * 8];
#pragma unroll
                for (int mt = 0; mt < 4; mt++)
#pragma unroll
                    for (int nt = 0; nt < 2; nt++)
                        O[mt][nt] = __builtin_amdgcn_mfma_f32_16x16x32_bf16(
                            ap[mt], bv[nt], O[mt][nt], 0, 0, 0);
            }
        }
    }

    // ---- epilogue: y = O / l (bf16) ----
#pragma unroll
    for (int mt = 0; mt < 4; mt++)
#pragma unroll
        for (int rr = 0; rr < 4; rr++) {
            const float inv = 1.0f / l_i[mt * 4 + rr];
            const int row = q0 + mt * 16 + quad * 4 + rr;
#pragma unroll
            for (int nt = 0; nt < 2; nt++)
                yh[((size_t)row * 16 + h) * 128 + wn + nt * 16 + fr] =
                    __float2bfloat16(O[mt][nt][rr] * inv);
        }
}

// ---------------------------------------------------------------------------
// Workspace (peak < 85 MB):
//  A  @0        : xh(8.39) xl(8.39) -> yh@0, vT@8.39
//  AR @16.78    : (16.78) GEMM temporaries -> woh
//  persistent   : qh@33.55 ql@46.14 knh@58.72 knl@67.11 vh@75.50
//                 kpeh@83.89 kpel@84.15
// ---------------------------------------------------------------------------
extern "C" void kernel_launch(void* const* d_in, const int* in_sizes, int n_in,
                              void* d_out, int out_size, void* d_ws, size_t ws_size,
                              hipStream_t stream)
{
    const float* x        = (const float*)d_in[0];
    const float* freqs    = (const float*)d_in[1];
    const float* wq_a     = (const float*)d_in[3];
    const float* q_norm_w = (const float*)d_in[4];
    const float* wq_b     = (const float*)d_in[5];
    const float* wkv_a    = (const float*)d_in[6];
    const float* kv_norm_w= (const float*)d_in[7];
    const float* wkv_b    = (const float*)d_in[8];
    const float* wo       = (const float*)d_in[9];
    float* out            = (float*)d_out;

    char* ws = (char*)d_ws;
    bf* xh = (bf*)(ws);
    bf* xl = (bf*)(ws + 8388608);
    bf* yh = (bf*)(ws);                   // after x dead
    bf* vT = (bf*)(ws + 8388608);         // after x dead
    char* AR = ws + 16777216;
    bf*    wah    = (bf*)(AR);
    bf*    wal    = (bf*)(AR + 3145728);
    float* qa     = (float*)(AR + 6291456);
    bf*    qah    = (bf*)(AR);
    bf*    qal    = (bf*)(AR + 3145728);
    bf*    wbh    = (bf*)(AR + 6291456);
    bf*    wbl    = (bf*)(AR + 11010048);
    bf*    kah    = (bf*)(AR);
    bf*    kal    = (bf*)(AR + 2359296);
    float* kvfull = (float*)(AR + 4718592);
    bf*    ckvh   = (bf*)(AR + 9437184);
    bf*    ckvl   = (bf*)(AR + 11534336);
    bf*    wvh    = (bf*)(AR);
    bf*    wvl    = (bf*)(AR + 4194304);
    bf*    woh    = (bf*)(AR);
    bf* qh   = (bf*)(ws + 33554432);
    bf* ql   = (bf*)(ws + 46137344);
    bf* knh  = (bf*)(ws + 58720256);
    bf* knl  = (bf*)(ws + 67108864);
    bf* vh   = (bf*)(ws + 75497472);
    bf* kpeh = (bf*)(ws + 83886080);
    bf* kpel = (bf*)(ws + 84148224);

    dim3 blk(256);

    cvt_split<<<4096, blk, 0, stream>>>(x, xh, xl, D_MODEL * D_MODEL);
    cvt_split<<<1536, blk, 0, stream>>>(wq_a, wah, wal, QLORA * D_MODEL);
    gemm_split64<<<dim3(12, 32), blk, 0, stream>>>(
        xh, xl, wah, wal, qa, T_DIM, QLORA, D_MODEL);
    rmsnorm_cvt<<<T_DIM, blk, 0, stream>>>(qa, QLORA, QLORA, q_norm_w, qah, qal);
    cvt_split<<<2304, blk, 0, stream>>>(wq_b, wbh, wbl, 3072 * QLORA);
    gemm_split<1><<<dim3(24, 16), blk, 0, stream>>>(
        qah, qal, wbh, wbl, freqs, nullptr, qh, ql, nullptr,
        T_DIM, 3072, QLORA);
    cvt_split<<<1152, blk, 0, stream>>>(wkv_a, kah, kal, KVFULL_D * D_MODEL);
    gemm_split64<<<dim3(9, 32), blk, 0, stream>>>(
        xh, xl, kah, kal, kvfull, T_DIM, KVFULL_D, D_MODEL);
    rope_k_cvt<<<256, blk, 0, stream>>>(kvfull, freqs, kpeh, kpel);
    rmsnorm_cvt<<<T_DIM, blk, 0, stream>>>(kvfull, KVFULL_D, KVLORA, kv_norm_w, ckvh, ckvl);
    cvt_split<<<2048, blk, 0, stream>>>(wkv_b, wvh, wvl, 4096 * KVLORA);
    gemm_split<2><<<dim3(32, 16), blk, 0, stream>>>(
        ckvh, ckvl, wvh, wvl, nullptr, nullptr, knh, knl, vh,
        T_DIM, 4096, KVLORA);
    transpose_v<<<dim3(64, 4, 16), blk, 0, stream>>>(vh, vT);
    attn_mfma<<<dim3(512), blk, 0, stream>>>(
        qh, ql, knh, knl, kpeh, kpel, vT, yh);
    cvt_hi<<<4096, blk, 0, stream>>>(wo, woh, D_MODEL * D_MODEL);
    gemm_bf16<<<dim3(16, 16), blk, 0, stream>>>(
        yh, woh, out, T_DIM, D_MODEL, D_MODEL);
}

// Round 11
// 613.372 us; speedup vs baseline: 1.1467x; 1.0146x over previous
//
#include <hip/hip_runtime.h>
#include <hip/hip_bf16.h>
#include <math.h>

// ---------------------------------------------------------------------------
// DeepSeek MLA forward. Round 20:
//  - R19 banked (622.4 us): BK=64 on all five GEMMs; attn frozen at R9 fabric
//    (266 us, FETCH 122 MB — do NOT touch; R10-R18 all degraded it).
//  - R20: the three projection GEMMs run at ~1-2 blocks/CU, so their per-iter
//    drain barriers are exposed (waves in a block share the barrier; only
//    independent blocks overlap drains). N-halve tiles 128x128 -> 128x64:
//      gemm_bf16     grid 256 -> 512  (LDS 24 KB, 2/CU)
//      gemm_split<1> grid 384 -> 768  (LDS 48 KB, 3/CU)
//      gemm_split<2> grid 512 -> 1024 (LDS 48 KB, 3/CU)
//    N-split preserves every output element's K-accumulation chain bitwise
//    -> absmax identical. Cost: A-panel staged traffic x2 (L2-served).
//  - Everything else byte-identical to R19.
// ---------------------------------------------------------------------------

#define T_DIM 2048
#define HEADS 16
#define D_MODEL 2048
#define NOPE_D 128
#define ROPE_D 64
#define QKD_D 192
#define VD_D 128
#define QLORA 768
#define KVLORA 512
#define KVFULL_D 576
#define SOFTSCALE -96.0f
#define EPS_RMS 1e-6f

typedef __hip_bfloat16 bf;
typedef __attribute__((ext_vector_type(8))) short bf16x8;
typedef __attribute__((ext_vector_type(4))) float f32x4;

#define GLOAD_LDS16(gptr, lptr)                                               \
    __builtin_amdgcn_global_load_lds(                                         \
        (const __attribute__((address_space(1))) unsigned int*)(gptr),        \
        (__attribute__((address_space(3))) unsigned int*)(lptr), 16, 0, 0)

__device__ __forceinline__ void split2(float v, bf* hi, bf* lo) {
    bf h = __float2bfloat16(v);
    *hi = h;
    *lo = __float2bfloat16(v - __bfloat162float(h));
}

// ---------------------------------------------------------------------------
__global__ __launch_bounds__(256) void cvt_split(
    const float* __restrict__ in, bf* __restrict__ hi, bf* __restrict__ lo, int n)
{
    const int i = (blockIdx.x * 256 + threadIdx.x) * 4;
    if (i >= n) return;
    float4 v = *(const float4*)&in[i];
    float vv[4] = {v.x, v.y, v.z, v.w};
#pragma unroll
    for (int u = 0; u < 4; u++) split2(vv[u], &hi[i + u], &lo[i + u]);
}

__global__ __launch_bounds__(256) void cvt_hi(
    const float* __restrict__ in, bf* __restrict__ hi, int n)
{
    const int i = (blockIdx.x * 256 + threadIdx.x) * 4;
    if (i >= n) return;
    float4 v = *(const float4*)&in[i];
    hi[i + 0] = __float2bfloat16(v.x);
    hi[i + 1] = __float2bfloat16(v.y);
    hi[i + 2] = __float2bfloat16(v.z);
    hi[i + 3] = __float2bfloat16(v.w);
}

// ---------------------------------------------------------------------------
__global__ __launch_bounds__(256) void rmsnorm_cvt(
    const float* __restrict__ in, int ld, int D, const float* __restrict__ w,
    bf* __restrict__ hi, bf* __restrict__ lo)
{
    const int row = blockIdx.x;
    const float* r = in + (size_t)row * ld;
    float ss = 0.0f;
    for (int i = threadIdx.x; i < D; i += 256) { float v = r[i]; ss += v * v; }
#pragma unroll
    for (int o = 32; o > 0; o >>= 1) ss += __shfl_down(ss, o, 64);
    __shared__ float red[4];
    if ((threadIdx.x & 63) == 0) red[threadIdx.x >> 6] = ss;
    __syncthreads();
    ss = red[0] + red[1] + red[2] + red[3];
    const float scale = rsqrtf(ss / (float)D + EPS_RMS);
    for (int i = threadIdx.x; i < D; i += 256) {
        const float v = r[i] * scale * w[i];
        split2(v, &hi[(size_t)row * D + i], &lo[(size_t)row * D + i]);
    }
}

// ---------------------------------------------------------------------------
__global__ __launch_bounds__(256) void rope_k_cvt(
    const float* __restrict__ kvfull, const float* __restrict__ freqs,
    bf* __restrict__ kpeh, bf* __restrict__ kpel)
{
    const int idx = blockIdx.x * 256 + threadIdx.x;   // 65536
    const int i = idx & 31, t = idx >> 5;
    const float f = freqs[t * 32 + i];
    float sn, cs; sincosf(f, &sn, &cs);
    const float x1 = kvfull[(size_t)t * KVFULL_D + KVLORA + 2 * i];
    const float x2 = kvfull[(size_t)t * KVFULL_D + KVLORA + 2 * i + 1];
    split2(x1 * cs - x2 * sn, &kpeh[t * 64 + 2 * i], &kpel[t * 64 + 2 * i]);
    split2(x1 * sn + x2 * cs, &kpeh[t * 64 + 2 * i + 1], &kpel[t * 64 + 2 * i + 1]);
}

// ---------------------------------------------------------------------------
__global__ __launch_bounds__(256) void transpose_v(
    const bf* __restrict__ vh, bf* __restrict__ vT)
{
    __shared__ bf s[32][33];
    const int t0 = blockIdx.x * 32, d0 = blockIdx.y * 32, h = blockIdx.z;
    const int tid = threadIdx.x;
    const int i = tid >> 3, j0 = (tid & 7) * 4;
    const bf* src = vh + ((size_t)(t0 + i) * 16 + h) * 128 + d0 + j0;
#pragma unroll
    for (int u = 0; u < 4; u++) s[i][j0 + u] = src[u];
    __syncthreads();
    const int jj = tid >> 3, i0 = (tid & 7) * 4;
    bf* dst = vT + ((size_t)h * 128 + d0 + jj) * 2048 + t0 + i0;
#pragma unroll
    for (int u = 0; u < 4; u++) dst[u] = s[i0 + u][jj];
}

// ---------------------------------------------------------------------------
// Split-bf16 GEMM (score path), 128x64 tile (R20), BK=64, 3 MFMAs.
// MODE 1: RoPE on d>=128 + split -> Oh/Ol (q). MODE 2: kn/v split write.
// LDS: sA 2x[2ks][128][32]=16K each, sB 2x[2ks][64][32]=8K each -> 48 KB
// (3 blocks/CU). 4 waves in 2x2: wave owns 64 rows x 32 cols (acc[4][2]).
// Per-element K-accumulation order identical to the 128x128 version.
// ---------------------------------------------------------------------------
template <int MODE>
__global__ __launch_bounds__(256) void gemm_split(
    const bf* __restrict__ Ah, const bf* __restrict__ Al,
    const bf* __restrict__ Bh, const bf* __restrict__ Bl,
    const float* __restrict__ freqs,
    float* __restrict__ Cf, bf* __restrict__ Oh, bf* __restrict__ Ol,
    bf* __restrict__ O2, int M, int N, int K)
{
    __shared__ bf sAh[2 * 128 * 32], sAl[2 * 128 * 32];
    __shared__ bf sBh[2 * 64 * 32],  sBl[2 * 64 * 32];

    const int tid = threadIdx.x;
    const int lane = tid & 63, wave = tid >> 6;
    const int row0 = blockIdx.y * 128, col0 = blockIdx.x * 64;
    const int wm = (wave & 1) * 64, wn = (wave >> 1) * 32;
    const int fr = lane & 15, quad = lane >> 4;

    f32x4 acc[4][2];
#pragma unroll
    for (int i = 0; i < 4; i++)
#pragma unroll
        for (int j = 0; j < 2; j++) acc[i][j] = (f32x4){0.f, 0.f, 0.f, 0.f};

    const int trow = tid >> 2;
    const int tcol = (tid & 3) * 8;
    const size_t ldsoff = (size_t)wave * 1024;

    for (int kt = 0; kt < K; kt += 64) {
        __syncthreads();
#pragma unroll
        for (int ks = 0; ks < 2; ks++) {
            const int kk = kt + ks * 32;
            GLOAD_LDS16(Ah + (size_t)(row0 + trow) * K + kk + tcol,      (char*)sAh + ks * 8192 + ldsoff);
            GLOAD_LDS16(Ah + (size_t)(row0 + 64 + trow) * K + kk + tcol, (char*)sAh + ks * 8192 + 4096 + ldsoff);
            GLOAD_LDS16(Al + (size_t)(row0 + trow) * K + kk + tcol,      (char*)sAl + ks * 8192 + ldsoff);
            GLOAD_LDS16(Al + (size_t)(row0 + 64 + trow) * K + kk + tcol, (char*)sAl + ks * 8192 + 4096 + ldsoff);
            GLOAD_LDS16(Bh + (size_t)(col0 + trow) * K + kk + tcol,      (char*)sBh + ks * 4096 + ldsoff);
            GLOAD_LDS16(Bl + (size_t)(col0 + trow) * K + kk + tcol,      (char*)sBl + ks * 4096 + ldsoff);
        }
        __syncthreads();

#pragma unroll
        for (int ks = 0; ks < 2; ks++) {
            bf16x8 a_h[4], a_l[4], b_h[2], b_l[2];
#pragma unroll
            for (int mt = 0; mt < 4; mt++) {
                const int r = ks * 4096 + (wm + mt * 16 + fr) * 32 + quad * 8;
                a_h[mt] = *(const bf16x8*)&sAh[r];
                a_l[mt] = *(const bf16x8*)&sAl[r];
            }
#pragma unroll
            for (int nt = 0; nt < 2; nt++) {
                const int r = ks * 2048 + (wn + nt * 16 + fr) * 32 + quad * 8;
                b_h[nt] = *(const bf16x8*)&sBh[r];
                b_l[nt] = *(const bf16x8*)&sBl[r];
            }
#pragma unroll
            for (int mt = 0; mt < 4; mt++)
#pragma unroll
                for (int nt = 0; nt < 2; nt++) {
                    acc[mt][nt] = __builtin_amdgcn_mfma_f32_16x16x32_bf16(
                        a_l[mt], b_h[nt], acc[mt][nt], 0, 0, 0);
                    acc[mt][nt] = __builtin_amdgcn_mfma_f32_16x16x32_bf16(
                        a_h[mt], b_l[nt], acc[mt][nt], 0, 0, 0);
                    acc[mt][nt] = __builtin_amdgcn_mfma_f32_16x16x32_bf16(
                        a_h[mt], b_h[nt], acc[mt][nt], 0, 0, 0);
                }
        }
    }

#pragma unroll
    for (int mt = 0; mt < 4; mt++)
#pragma unroll
        for (int nt = 0; nt < 2; nt++) {
            const int colb = col0 + wn + nt * 16;
            const int col = colb + fr;
            if (MODE == 1) {
                const int d0 = colb % 192;
                const bool rope = (d0 >= 128);
                const int ii = (d0 + fr - 128) >> 1;
#pragma unroll
                for (int r = 0; r < 4; r++) {
                    const int row = row0 + wm + mt * 16 + quad * 4 + r;
                    float v = acc[mt][nt][r];
                    if (rope) {
                        const float other = __shfl_xor(v, 1);
                        float sn, cs; sincosf(freqs[row * 32 + ii], &sn, &cs);
                        v = (fr & 1) ? (other * sn + v * cs) : (v * cs - other * sn);
                    }
                    bf h8, l8; split2(v, &h8, &l8);
                    Oh[(size_t)row * N + col] = h8;
                    Ol[(size_t)row * N + col] = l8;
                }
            } else {
                const int hh = col >> 8;
                const int d = col & 255;
#pragma unroll
                for (int r = 0; r < 4; r++) {
                    const int row = row0 + wm + mt * 16 + quad * 4 + r;
                    const float v = acc[mt][nt][r];
                    if (d < 128) {
                        bf h8, l8; split2(v, &h8, &l8);
                        Oh[(size_t)row * 2048 + hh * 128 + d] = h8;
                        Ol[(size_t)row * 2048 + hh * 128 + d] = l8;
                    } else {
                        O2[(size_t)row * 2048 + hh * 128 + (d - 128)] = __float2bfloat16(v);
                    }
                }
            }
        }
}

// ---------------------------------------------------------------------------
// Split-bf16 GEMM, 64x64 tile, BK=64 (R15): halves drain-barrier count on the
// two K=2048 shapes (qa N=768, kvfull N=576). LDS [2 ks][64][32] per array.
// ---------------------------------------------------------------------------
__global__ __launch_bounds__(256) void gemm_split64(
    const bf* __restrict__ Ah, const bf* __restrict__ Al,
    const bf* __restrict__ Bh, const bf* __restrict__ Bl,
    float* __restrict__ Cf, int M, int N, int K)
{
    __shared__ bf sAh[2 * 64 * 32], sAl[2 * 64 * 32];
    __shared__ bf sBh[2 * 64 * 32], sBl[2 * 64 * 32];

    const int tid = threadIdx.x;
    const int lane = tid & 63, wave = tid >> 6;
    const int row0 = blockIdx.y * 64, col0 = blockIdx.x * 64;
    const int wm = (wave & 1) * 32, wn = (wave >> 1) * 32;
    const int fr = lane & 15, quad = lane >> 4;

    f32x4 acc[2][2];
#pragma unroll
    for (int i = 0; i < 2; i++)
#pragma unroll
        for (int j = 0; j < 2; j++) acc[i][j] = (f32x4){0.f, 0.f, 0.f, 0.f};

    const int trow = tid >> 2;
    const int tcol = (tid & 3) * 8;
    const size_t ldsoff = (size_t)wave * 1024;

    for (int kt = 0; kt < K; kt += 64) {
        __syncthreads();
        GLOAD_LDS16(Ah + (size_t)(row0 + trow) * K + kt + tcol,      (char*)sAh + ldsoff);
        GLOAD_LDS16(Ah + (size_t)(row0 + trow) * K + kt + 32 + tcol, (char*)sAh + 4096 + ldsoff);
        GLOAD_LDS16(Al + (size_t)(row0 + trow) * K + kt + tcol,      (char*)sAl + ldsoff);
        GLOAD_LDS16(Al + (size_t)(row0 + trow) * K + kt + 32 + tcol, (char*)sAl + 4096 + ldsoff);
        GLOAD_LDS16(Bh + (size_t)(col0 + trow) * K + kt + tcol,      (char*)sBh + ldsoff);
        GLOAD_LDS16(Bh + (size_t)(col0 + trow) * K + kt + 32 + tcol, (char*)sBh + 4096 + ldsoff);
        GLOAD_LDS16(Bl + (size_t)(col0 + trow) * K + kt + tcol,      (char*)sBl + ldsoff);
        GLOAD_LDS16(Bl + (size_t)(col0 + trow) * K + kt + 32 + tcol, (char*)sBl + 4096 + ldsoff);
        __syncthreads();

#pragma unroll
        for (int ks = 0; ks < 2; ks++) {
            bf16x8 a_h[2], a_l[2], b_h[2], b_l[2];
#pragma unroll
            for (int mt = 0; mt < 2; mt++) {
                const int r = ks * 2048 + (wm + mt * 16 + fr) * 32 + quad * 8;
                a_h[mt] = *(const bf16x8*)&sAh[r];
                a_l[mt] = *(const bf16x8*)&sAl[r];
            }
#pragma unroll
            for (int nt = 0; nt < 2; nt++) {
                const int r = ks * 2048 + (wn + nt * 16 + fr) * 32 + quad * 8;
                b_h[nt] = *(const bf16x8*)&sBh[r];
                b_l[nt] = *(const bf16x8*)&sBl[r];
            }
#pragma unroll
            for (int mt = 0; mt < 2; mt++)
#pragma unroll
                for (int nt = 0; nt < 2; nt++) {
                    acc[mt][nt] = __builtin_amdgcn_mfma_f32_16x16x32_bf16(
                        a_l[mt], b_h[nt], acc[mt][nt], 0, 0, 0);
                    acc[mt][nt] = __builtin_amdgcn_mfma_f32_16x16x32_bf16(
                        a_h[mt], b_l[nt], acc[mt][nt], 0, 0, 0);
                    acc[mt][nt] = __builtin_amdgcn_mfma_f32_16x16x32_bf16(
                        a_h[mt], b_h[nt], acc[mt][nt], 0, 0, 0);
                }
        }
    }

#pragma unroll
    for (int mt = 0; mt < 2; mt++)
#pragma unroll
        for (int nt = 0; nt < 2; nt++)
#pragma unroll
            for (int r = 0; r < 4; r++)
                Cf[(size_t)(row0 + wm + mt * 16 + quad * 4 + r) * N +
                   col0 + wn + nt * 16 + fr] = acc[mt][nt][r];
}

// ---------------------------------------------------------------------------
// Plain bf16 GEMM (post-softmax out-projection): C = A @ B^T, single MFMA.
// 128x64 tile (R20), BK=64. LDS sA 16K + sB 8K = 24 KB -> grid 512 = 2/CU.
// ---------------------------------------------------------------------------
__global__ __launch_bounds__(256) void gemm_bf16(
    const bf* __restrict__ Ah, const bf* __restrict__ Bh,
    float* __restrict__ Cf, int M, int N, int K)
{
    __shared__ bf sAh[2 * 128 * 32];
    __shared__ bf sBh[2 * 64 * 32];

    const int tid = threadIdx.x;
    const int lane = tid & 63, wave = tid >> 6;
    const int row0 = blockIdx.y * 128, col0 = blockIdx.x * 64;
    const int wm = (wave & 1) * 64, wn = (wave >> 1) * 32;
    const int fr = lane & 15, quad = lane >> 4;

    f32x4 acc[4][2];
#pragma unroll
    for (int i = 0; i < 4; i++)
#pragma unroll
        for (int j = 0; j < 2; j++) acc[i][j] = (f32x4){0.f, 0.f, 0.f, 0.f};

    const int trow = tid >> 2;
    const int tcol = (tid & 3) * 8;
    const size_t ldsoff = (size_t)wave * 1024;

    for (int kt = 0; kt < K; kt += 64) {
        __syncthreads();
#pragma unroll
        for (int ks = 0; ks < 2; ks++) {
            const int kk = kt + ks * 32;
            GLOAD_LDS16(Ah + (size_t)(row0 + trow) * K + kk + tcol,      (char*)sAh + ks * 8192 + ldsoff);
            GLOAD_LDS16(Ah + (size_t)(row0 + 64 + trow) * K + kk + tcol, (char*)sAh + ks * 8192 + 4096 + ldsoff);
            GLOAD_LDS16(Bh + (size_t)(col0 + trow) * K + kk + tcol,      (char*)sBh + ks * 4096 + ldsoff);
        }
        __syncthreads();

#pragma unroll
        for (int ks = 0; ks < 2; ks++) {
            bf16x8 a_h[4], b_h[2];
#pragma unroll
            for (int mt = 0; mt < 4; mt++)
                a_h[mt] = *(const bf16x8*)&sAh[ks * 4096 + (wm + mt * 16 + fr) * 32 + quad * 8];
#pragma unroll
            for (int nt = 0; nt < 2; nt++)
                b_h[nt] = *(const bf16x8*)&sBh[ks * 2048 + (wn + nt * 16 + fr) * 32 + quad * 8];
#pragma unroll
            for (int mt = 0; mt < 4; mt++)
#pragma unroll
                for (int nt = 0; nt < 2; nt++)
                    acc[mt][nt] = __builtin_amdgcn_mfma_f32_16x16x32_bf16(
                        a_h[mt], b_h[nt], acc[mt][nt], 0, 0, 0);
        }
    }

#pragma unroll
    for (int mt = 0; mt < 4; mt++)
#pragma unroll
        for (int nt = 0; nt < 2; nt++)
#pragma unroll
            for (int r = 0; r < 4; r++)
                Cf[(size_t)(row0 + wm + mt * 16 + quad * 4 + r) * N +
                   col0 + wn + nt * 16 + fr] = acc[mt][nt][r];
}

// ---------------------------------------------------------------------------
// Monolithic MFMA flash attention (EXACT R9/R15 revert — FROZEN).
// 512 blocks = (h, qt), heavy/light paired. Per 128-key k-tile: ping-pong
// staged S (6 chunks x 1 barrier), fp32 online softmax, PV with padded Ps
// (stride 72) + preloaded V pairs. LDS 60.4 KB -> 2 blocks/CU. (256,2).
// Do NOT restructure: R10-R14, R16-R18 all degraded FETCH 1.4-3x.
// ---------------------------------------------------------------------------
__global__ __launch_bounds__(256, 2) void attn_mfma(
    const bf* __restrict__ qh, const bf* __restrict__ ql,
    const bf* __restrict__ knh, const bf* __restrict__ knl,
    const bf* __restrict__ kpeh, const bf* __restrict__ kpel,
    const bf* __restrict__ vT, bf* __restrict__ yh)
{
    const int bid = blockIdx.x;
    const int h = bid & 15;
    const int qt = (bid < 256) ? (31 - (bid >> 4)) : ((bid - 256) >> 4);

    const int tid = threadIdx.x;
    const int lane = tid & 63, wave = tid >> 6;
    const int fr = lane & 15, quad = lane >> 4;
    const int wn = wave * 32;

    // buf0 @0, buf1 @24576 (each: Qh 0 / Ql 4096 / Kh 8192 / Kl 16384)
    // sVt aliases buf0[0:16384] during PV. Ps @49152 ([64][72] bf16).
    __shared__ __align__(16) char smem[60416];
    bf* Ps  = (bf*)(smem + 49152);
    float* redM = (float*)(smem + 58368); // [64][4]
    float* redS = (float*)(smem + 59392); // [64][4]

    float m_i[16], l_i[16], al[16];
    f32x4 O[4][2];
#pragma unroll
    for (int i = 0; i < 16; i++) { m_i[i] = -INFINITY; l_i[i] = 0.0f; }
#pragma unroll
    for (int mt = 0; mt < 4; mt++)
#pragma unroll
        for (int nt = 0; nt < 2; nt++) O[mt][nt] = (f32x4){0.f, 0.f, 0.f, 0.f};

    const int q0 = qt * 64;
    const int nkt = ((qt + 1) * 64 + 127) >> 7;
    const int trow = tid >> 2, tcol = (tid & 3) * 8;
    const size_t loff = (size_t)wave * 1024;

    for (int kt = 0; kt < nkt; kt++) {
        const int k0 = kt * 128;
        f32x4 S[4][2];
#pragma unroll
        for (int mt = 0; mt < 4; mt++)
#pragma unroll
            for (int nt = 0; nt < 2; nt++) S[mt][nt] = (f32x4){0.f, 0.f, 0.f, 0.f};

        // leading barrier: prior k-tile's PV readers of buf0 (sVt alias) done
        __syncthreads();

        // ---- S = Q.K^T over 192 dims: 6 chunks, ping-pong, 1 barrier each --
        for (int ch = 0; ch < 6; ch++) {
            const int d0 = ch * 32;
            char* buf = smem + ((ch & 1) ? 24576 : 0);
            GLOAD_LDS16(qh + ((size_t)(q0 + trow) * 16 + h) * 192 + d0 + tcol, buf + loff);
            GLOAD_LDS16(ql + ((size_t)(q0 + trow) * 16 + h) * 192 + d0 + tcol, buf + 4096 + loff);
            if (d0 < 128) {
                GLOAD_LDS16(knh + ((size_t)(k0 + trow) * 16 + h) * 128 + d0 + tcol,      buf + 8192 + loff);
                GLOAD_LDS16(knh + ((size_t)(k0 + 64 + trow) * 16 + h) * 128 + d0 + tcol, buf + 12288 + loff);
                GLOAD_LDS16(knl + ((size_t)(k0 + trow) * 16 + h) * 128 + d0 + tcol,      buf + 16384 + loff);
                GLOAD_LDS16(knl + ((size_t)(k0 + 64 + trow) * 16 + h) * 128 + d0 + tcol, buf + 20480 + loff);
            } else {
                GLOAD_LDS16(kpeh + (size_t)(k0 + trow) * 64 + (d0 - 128) + tcol,      buf + 8192 + loff);
                GLOAD_LDS16(kpeh + (size_t)(k0 + 64 + trow) * 64 + (d0 - 128) + tcol, buf + 12288 + loff);
                GLOAD_LDS16(kpel + (size_t)(k0 + trow) * 64 + (d0 - 128) + tcol,      buf + 16384 + loff);
                GLOAD_LDS16(kpel + (size_t)(k0 + 64 + trow) * 64 + (d0 - 128) + tcol, buf + 20480 + loff);
            }
            __syncthreads();

            const bf* sQh = (const bf*)buf;
            const bf* sQl = (const bf*)(buf + 4096);
            const bf* sKh = (const bf*)(buf + 8192);
            const bf* sKl = (const bf*)(buf + 16384);
            bf16x8 a_h[4], a_l[4], b_h[2], b_l[2];
#pragma unroll
            for (int mt = 0; mt < 4; mt++) {
                const int r = (mt * 16 + fr) * 32 + quad * 8;
                a_h[mt] = *(const bf16x8*)&sQh[r];
                a_l[mt] = *(const bf16x8*)&sQl[r];
            }
#pragma unroll
            for (int nt = 0; nt < 2; nt++) {
                const int r = (wn + nt * 16 + fr) * 32 + quad * 8;
                b_h[nt] = *(const bf16x8*)&sKh[r];
                b_l[nt] = *(const bf16x8*)&sKl[r];
            }
#pragma unroll
            for (int mt = 0; mt < 4; mt++)
#pragma unroll
                for (int nt = 0; nt < 2; nt++) {
                    S[mt][nt] = __builtin_amdgcn_mfma_f32_16x16x32_bf16(
                        a_l[mt], b_h[nt], S[mt][nt], 0, 0, 0);
                    S[mt][nt] = __builtin_amdgcn_mfma_f32_16x16x32_bf16(
                        a_h[mt], b_l[nt], S[mt][nt], 0, 0, 0);
                    S[mt][nt] = __builtin_amdgcn_mfma_f32_16x16x32_bf16(
                        a_h[mt], b_h[nt], S[mt][nt], 0, 0, 0);
                }
        }

        // ---- online softmax (fp32, block-wide row reductions) ----
#pragma unroll
        for (int mt = 0; mt < 4; mt++)
#pragma unroll
            for (int rr = 0; rr < 4; rr++) {
                const int ri = mt * 16 + quad * 4 + rr;
                const int rowg = q0 + ri;
                float v0 = S[mt][0][rr] * SOFTSCALE;
                float v1 = S[mt][1][rr] * SOFTSCALE;
                if (k0 + wn + fr > rowg)      v0 = -INFINITY;
                if (k0 + wn + 16 + fr > rowg) v1 = -INFINITY;
                S[mt][0][rr] = v0; S[mt][1][rr] = v1;
                float pm = fmaxf(v0, v1);
#pragma unroll
                for (int o = 1; o < 16; o <<= 1) pm = fmaxf(pm, __shfl_xor(pm, o, 64));
                if (fr == 0) redM[ri * 4 + wave] = pm;
            }
        __syncthreads();
#pragma unroll
        for (int mt = 0; mt < 4; mt++)
#pragma unroll
            for (int rr = 0; rr < 4; rr++) {
                const int idx = mt * 4 + rr;
                const int ri = mt * 16 + quad * 4 + rr;
                const float4 g = *(const float4*)&redM[ri * 4];
                const float gm = fmaxf(fmaxf(g.x, g.y), fmaxf(g.z, g.w));
                const float mn = fmaxf(m_i[idx], gm);
                al[idx] = __expf(m_i[idx] - mn);
                m_i[idx] = mn;
                const float p0 = __expf(S[mt][0][rr] - mn);
                const float p1 = __expf(S[mt][1][rr] - mn);
                S[mt][0][rr] = p0; S[mt][1][rr] = p1;   // keep p for PV store
                float ps = p0 + p1;
#pragma unroll
                for (int o = 1; o < 16; o <<= 1) ps += __shfl_xor(ps, o, 64);
                if (fr == 0) redS[ri * 4 + wave] = ps;
            }
#pragma unroll
        for (int mt = 0; mt < 4; mt++)
#pragma unroll
            for (int nt = 0; nt < 2; nt++)
#pragma unroll
                for (int rr = 0; rr < 4; rr++) O[mt][nt][rr] *= al[mt * 4 + rr];
        __syncthreads();
#pragma unroll
        for (int mt = 0; mt < 4; mt++)
#pragma unroll
            for (int rr = 0; rr < 4; rr++) {
                const int idx = mt * 4 + rr;
                const int ri = mt * 16 + quad * 4 + rr;
                const float4 s4 = *(const float4*)&redS[ri * 4];
                l_i[idx] = l_i[idx] * al[idx] + (s4.x + s4.y + s4.z + s4.w);
            }

        // ---- PV: two 64-key halves; both 32-key V chunks preloaded ----
        bf* sVt = (bf*)smem;   // aliases buf0 (dead during PV)
#pragma unroll
        for (int half = 0; half < 2; half++) {
            if (half) __syncthreads();   // prior Ps/sVt readers done
            if ((wave >> 1) == half) {
                const int kc = wn - half * 64;   // 0 or 32
#pragma unroll
                for (int mt = 0; mt < 4; mt++)
#pragma unroll
                    for (int rr = 0; rr < 4; rr++) {
                        const int ri = mt * 16 + quad * 4 + rr;
                        Ps[ri * 72 + kc + fr]      = __float2bfloat16(S[mt][0][rr]);
                        Ps[ri * 72 + kc + 16 + fr] = __float2bfloat16(S[mt][1][rr]);
                    }
            }
            const int kb = k0 + half * 64;
            GLOAD_LDS16(vT + ((size_t)(h * 128 + trow)) * 2048 + kb + tcol,           (char*)sVt + loff);
            GLOAD_LDS16(vT + ((size_t)(h * 128 + 64 + trow)) * 2048 + kb + tcol,      (char*)sVt + 4096 + loff);
            GLOAD_LDS16(vT + ((size_t)(h * 128 + trow)) * 2048 + kb + 32 + tcol,      (char*)sVt + 8192 + loff);
            GLOAD_LDS16(vT + ((size_t)(h * 128 + 64 + trow)) * 2048 + kb + 32 + tcol, (char*)sVt + 12288 + loff);
            __syncthreads();
#pragma unroll
            for (int vc = 0; vc < 2; vc++) {
                bf16x8 ap[4], bv[2];
#pragma unroll
                for (int mt = 0; mt < 4; mt++)
                    ap[mt] = *(const bf16x8*)&Ps[(mt * 16 + fr) * 72 + vc * 32 + quad * 8];
#pragma unroll
                for (int nt = 0; nt < 2; nt++)
                    bv[nt] = *(const bf16x8*)&sVt[vc * 4096 + (wn + nt * 16 + fr) * 32 + quad * 8];
#pragma unroll
                for (int mt = 0; mt < 4; mt++)
#pragma unroll
                    for (int nt = 0; nt < 2; nt++)
                        O[mt][nt] = __builtin_amdgcn_mfma_f32_16x16x32_bf16(
                            ap[mt], bv[nt], O[mt][nt], 0, 0, 0);
            }
        }
    }

    // ---- epilogue: y = O / l (bf16) ----
#pragma unroll
    for (int mt = 0; mt < 4; mt++)
#pragma unroll
        for (int rr = 0; rr < 4; rr++) {
            const float inv = 1.0f / l_i[mt * 4 + rr];
            const int row = q0 + mt * 16 + quad * 4 + rr;
#pragma unroll
            for (int nt = 0; nt < 2; nt++)
                yh[((size_t)row * 16 + h) * 128 + wn + nt * 16 + fr] =
                    __float2bfloat16(O[mt][nt][rr] * inv);
        }
}

// ---------------------------------------------------------------------------
// Workspace (peak < 85 MB):
//  A  @0        : xh(8.39) xl(8.39) -> yh@0, vT@8.39
//  AR @16.78    : (16.78) GEMM temporaries -> woh
//  persistent   : qh@33.55 ql@46.14 knh@58.72 knl@67.11 vh@75.50
//                 kpeh@83.89 kpel@84.15
// ---------------------------------------------------------------------------
extern "C" void kernel_launch(void* const* d_in, const int* in_sizes, int n_in,
                              void* d_out, int out_size, void* d_ws, size_t ws_size,
                              hipStream_t stream)
{
    const float* x        = (const float*)d_in[0];
    const float* freqs    = (const float*)d_in[1];
    const float* wq_a     = (const float*)d_in[3];
    const float* q_norm_w = (const float*)d_in[4];
    const float* wq_b     = (const float*)d_in[5];
    const float* wkv_a    = (const float*)d_in[6];
    const float* kv_norm_w= (const float*)d_in[7];
    const float* wkv_b    = (const float*)d_in[8];
    const float* wo       = (const float*)d_in[9];
    float* out            = (float*)d_out;

    char* ws = (char*)d_ws;
    bf* xh = (bf*)(ws);
    bf* xl = (bf*)(ws + 8388608);
    bf* yh = (bf*)(ws);                   // after x dead
    bf* vT = (bf*)(ws + 8388608);         // after x dead
    char* AR = ws + 16777216;
    bf*    wah    = (bf*)(AR);
    bf*    wal    = (bf*)(AR + 3145728);
    float* qa     = (float*)(AR + 6291456);
    bf*    qah    = (bf*)(AR);
    bf*    qal    = (bf*)(AR + 3145728);
    bf*    wbh    = (bf*)(AR + 6291456);
    bf*    wbl    = (bf*)(AR + 11010048);
    bf*    kah    = (bf*)(AR);
    bf*    kal    = (bf*)(AR + 2359296);
    float* kvfull = (float*)(AR + 4718592);
    bf*    ckvh   = (bf*)(AR + 9437184);
    bf*    ckvl   = (bf*)(AR + 11534336);
    bf*    wvh    = (bf*)(AR);
    bf*    wvl    = (bf*)(AR + 4194304);
    bf*    woh    = (bf*)(AR);
    bf* qh   = (bf*)(ws + 33554432);
    bf* ql   = (bf*)(ws + 46137344);
    bf* knh  = (bf*)(ws + 58720256);
    bf* knl  = (bf*)(ws + 67108864);
    bf* vh   = (bf*)(ws + 75497472);
    bf* kpeh = (bf*)(ws + 83886080);
    bf* kpel = (bf*)(ws + 84148224);

    dim3 blk(256);

    cvt_split<<<4096, blk, 0, stream>>>(x, xh, xl, D_MODEL * D_MODEL);
    cvt_split<<<1536, blk, 0, stream>>>(wq_a, wah, wal, QLORA * D_MODEL);
    gemm_split64<<<dim3(12, 32), blk, 0, stream>>>(
        xh, xl, wah, wal, qa, T_DIM, QLORA, D_MODEL);
    rmsnorm_cvt<<<T_DIM, blk, 0, stream>>>(qa, QLORA, QLORA, q_norm_w, qah, qal);
    cvt_split<<<2304, blk, 0, stream>>>(wq_b, wbh, wbl, 3072 * QLORA);
    gemm_split<1><<<dim3(48, 16), blk, 0, stream>>>(
        qah, qal, wbh, wbl, freqs, nullptr, qh, ql, nullptr,
        T_DIM, 3072, QLORA);
    cvt_split<<<1152, blk, 0, stream>>>(wkv_a, kah, kal, KVFULL_D * D_MODEL);
    gemm_split64<<<dim3(9, 32), blk, 0, stream>>>(
        xh, xl, kah, kal, kvfull, T_DIM, KVFULL_D, D_MODEL);
    rope_k_cvt<<<256, blk, 0, stream>>>(kvfull, freqs, kpeh, kpel);
    rmsnorm_cvt<<<T_DIM, blk, 0, stream>>>(kvfull, KVFULL_D, KVLORA, kv_norm_w, ckvh, ckvl);
    cvt_split<<<2048, blk, 0, stream>>>(wkv_b, wvh, wvl, 4096 * KVLORA);
    gemm_split<2><<<dim3(64, 16), blk, 0, stream>>>(
        ckvh, ckvl, wvh, wvl, nullptr, nullptr, knh, knl, vh,
        T_DIM, 4096, KVLORA);
    transpose_v<<<dim3(64, 4, 16), blk, 0, stream>>>(vh, vT);
    attn_mfma<<<dim3(512), blk, 0, stream>>>(
        qh, ql, knh, knl, kpeh, kpel, vT, yh);
    cvt_hi<<<4096, blk, 0, stream>>>(wo, woh, D_MODEL * D_MODEL);
    gemm_bf16<<<dim3(32, 16), blk, 0, stream>>>(
        yh, woh, out, T_DIM, D_MODEL, D_MODEL);
}